// Round 1
// baseline (812.669 us; speedup 1.0000x reference)
//
#include <hip/hip_runtime.h>
#include <math.h>

#define B_ 16
#define N_ 8192
#define H_ 128
#define T_ 256   // TOK_MLP
#define C_ 512   // CH_MLP

__device__ __forceinline__ float gelu_f(float x) {
    return 0.5f * x * (1.0f + erff(x * 0.70710678118654752f));
}

// ---------------- tok_w1 prefix cumsum (3 tiny kernels) ----------------
__global__ void k_w1_psum(const float* __restrict__ w1, float* __restrict__ psum) {
    int c = blockIdx.x, t = threadIdx.x;
    const float* p = w1 + (size_t)c * 64 * T_ + t;
    float s = 0.f;
    #pragma unroll 8
    for (int r = 0; r < 64; ++r) s += p[(size_t)r * T_];
    psum[c * T_ + t] = s;
}

__global__ void k_w1_scan(const float* __restrict__ psum, float* __restrict__ offs) {
    int t = threadIdx.x;
    float run = 0.f;
    for (int c = 0; c < 128; ++c) {
        offs[c * T_ + t] = run;
        run += psum[c * T_ + t];
    }
}

__global__ void k_w1_prefix(const float* __restrict__ w1, const float* __restrict__ offs,
                            float* __restrict__ w1c) {
    int c = blockIdx.x, t = threadIdx.x;
    float run = offs[c * T_ + t];
    const float* p = w1 + (size_t)c * 64 * T_ + t;
    float* q = w1c + (size_t)c * 64 * T_ + t;
    for (int r = 0; r < 64; ++r) { run += p[(size_t)r * T_]; q[(size_t)r * T_] = run; }
}

// ---------------- LayerNorm over H=128 (wave per row) ----------------
__global__ void k_ln(const float* __restrict__ x, const float* __restrict__ g,
                     const float* __restrict__ bb, float* __restrict__ y) {
    int wave = threadIdx.x >> 6, lane = threadIdx.x & 63;
    size_t row = (size_t)blockIdx.x * 4 + wave;
    const float* xr = x + row * H_;
    float2 v = *(const float2*)(xr + lane * 2);
    float s = v.x + v.y, ss = v.x * v.x + v.y * v.y;
    #pragma unroll
    for (int off = 32; off > 0; off >>= 1) {
        s += __shfl_xor(s, off);
        ss += __shfl_xor(ss, off);
    }
    float mean = s * (1.f / 128.f);
    float var = ss * (1.f / 128.f) - mean * mean;
    float rstd = rsqrtf(var + 1e-5f);
    float2 gg = *(const float2*)(g + lane * 2);
    float2 bv = *(const float2*)(bb + lane * 2);
    float2 o;
    o.x = (v.x - mean) * rstd * gg.x + bv.x;
    o.y = (v.y - mean) * rstd * gg.y + bv.y;
    *(float2*)(y + row * H_ + lane * 2) = o;
}

// ---------------- token GEMM1: g1p[kk] partial of y1^T @ W1c ----------------
// per b: A = y1[b] [K=8192 rows(n), M=128 cols(h)]; Bm = W1c [K, T=256]
// tile 64m x 128n, split-K 8
__global__ void k_tok1(const float* __restrict__ y1, const float* __restrict__ w1c_g,
                       float* __restrict__ g1p) {
    int nt = blockIdx.x;            // 0..1
    int mt = blockIdx.y;            // 0..1
    int bz = blockIdx.z;            // b*8 + kk
    int b  = bz >> 3, kk = bz & 7;
    const float* A  = y1 + (size_t)b * N_ * H_ + (size_t)mt * 64;
    const float* Bg = w1c_g + nt * 128;
    int kbase = kk * (N_ / 8);

    __shared__ float As[32 * 68];
    __shared__ float Bs[32 * 132];
    int tid = threadIdx.x;
    int tx = tid & 15, ty = tid >> 4;
    int m0 = tx * 4, n0 = ty * 4;
    float acc[4][8] = {};

    for (int k0 = kbase; k0 < kbase + N_ / 8; k0 += 32) {
        __syncthreads();
        #pragma unroll
        for (int i = 0; i < 2; ++i) {           // A chunk [32][64]
            int idx = tid + i * 256;
            int r = idx >> 4, c4 = idx & 15;
            float4 v = *(const float4*)(A + (size_t)(k0 + r) * H_ + c4 * 4);
            *(float4*)&As[r * 68 + c4 * 4] = v;
        }
        #pragma unroll
        for (int i = 0; i < 4; ++i) {           // B chunk [32][128]
            int idx = tid + i * 256;
            int r = idx >> 5, c4 = idx & 31;
            float4 v = *(const float4*)(Bg + (size_t)(k0 + r) * T_ + c4 * 4);
            *(float4*)&Bs[r * 132 + c4 * 4] = v;
        }
        __syncthreads();
        #pragma unroll 4
        for (int k = 0; k < 32; ++k) {
            float4 av  = *(const float4*)&As[k * 68 + m0];
            float4 blo = *(const float4*)&Bs[k * 132 + n0];
            float4 bhi = *(const float4*)&Bs[k * 132 + n0 + 64];
            #pragma unroll
            for (int i = 0; i < 4; ++i) {
                float a = ((const float*)&av)[i];
                acc[i][0] = fmaf(a, blo.x, acc[i][0]);
                acc[i][1] = fmaf(a, blo.y, acc[i][1]);
                acc[i][2] = fmaf(a, blo.z, acc[i][2]);
                acc[i][3] = fmaf(a, blo.w, acc[i][3]);
                acc[i][4] = fmaf(a, bhi.x, acc[i][4]);
                acc[i][5] = fmaf(a, bhi.y, acc[i][5]);
                acc[i][6] = fmaf(a, bhi.z, acc[i][6]);
                acc[i][7] = fmaf(a, bhi.w, acc[i][7]);
            }
        }
    }
    float* P = g1p + ((size_t)kk * B_ + b) * H_ * T_;
    int hg = mt * 64 + m0;
    int tg = nt * 128 + n0;
    #pragma unroll
    for (int i = 0; i < 4; ++i) {
        float4 v0 = { acc[i][0], acc[i][1], acc[i][2], acc[i][3] };
        float4 v1 = { acc[i][4], acc[i][5], acc[i][6], acc[i][7] };
        *(float4*)(P + (size_t)(hg + i) * T_ + tg)      = v0;
        *(float4*)(P + (size_t)(hg + i) * T_ + tg + 64) = v1;
    }
}

// combine split-K partials + bias + gelu -> g1
__global__ void k_tok1_fin(const float* __restrict__ g1p, const float* __restrict__ b1,
                           float* __restrict__ g1) {
    size_t fid = (size_t)blockIdx.x * 256 + threadIdx.x;   // f4 index
    size_t base = fid * 4;
    const size_t S = (size_t)B_ * H_ * T_;
    float4 a = *(const float4*)(g1p + base);
    #pragma unroll
    for (int kk = 1; kk < 8; ++kk) {
        float4 p = *(const float4*)(g1p + (size_t)kk * S + base);
        a.x += p.x; a.y += p.y; a.z += p.z; a.w += p.w;
    }
    int t = (int)(base & (T_ - 1));
    float4 bb = *(const float4*)(b1 + t);
    float4 o;
    o.x = gelu_f(a.x + bb.x);
    o.y = gelu_f(a.y + bb.y);
    o.z = gelu_f(a.z + bb.z);
    o.w = gelu_f(a.w + bb.w);
    *(float4*)(g1 + base) = o;
}

// ---------------- token GEMM2: y2[b][n][h] = g1[b] @ w2 + b2 (transposed store) ----------------
// A = g1[b] [M=128(h), K=256(t)] row-major; B = w2 [K=256, N=8192]
// tile 64m x 128n, K full
__global__ void k_tok2(const float* __restrict__ g1, const float* __restrict__ w2,
                       const float* __restrict__ b2, float* __restrict__ y2) {
    int nt = blockIdx.x;            // 0..63
    int mt = blockIdx.y;            // 0..1
    int b  = blockIdx.z;
    const float* A  = g1 + (size_t)b * H_ * T_ + (size_t)mt * 64 * T_;
    const float* Bg = w2 + (size_t)nt * 128;

    __shared__ float As[32 * 68];
    __shared__ float Bs[32 * 132];
    int tid = threadIdx.x;
    int tx = tid & 15, ty = tid >> 4;
    int m0 = tx * 4, n0 = ty * 4;
    float acc[4][8] = {};

    for (int k0 = 0; k0 < T_; k0 += 32) {
        __syncthreads();
        #pragma unroll
        for (int i = 0; i < 2; ++i) {           // A chunk [64m][32k] -> As[k][m]
            int idx = tid + i * 256;
            int m = idx >> 3, kq = idx & 7;
            float4 v = *(const float4*)(A + (size_t)m * T_ + k0 + kq * 4);
            As[(kq * 4 + 0) * 68 + m] = v.x;
            As[(kq * 4 + 1) * 68 + m] = v.y;
            As[(kq * 4 + 2) * 68 + m] = v.z;
            As[(kq * 4 + 3) * 68 + m] = v.w;
        }
        #pragma unroll
        for (int i = 0; i < 4; ++i) {           // B chunk [32][128]
            int idx = tid + i * 256;
            int r = idx >> 5, c4 = idx & 31;
            float4 v = *(const float4*)(Bg + (size_t)(k0 + r) * N_ + c4 * 4);
            *(float4*)&Bs[r * 132 + c4 * 4] = v;
        }
        __syncthreads();
        #pragma unroll 4
        for (int k = 0; k < 32; ++k) {
            float4 av  = *(const float4*)&As[k * 68 + m0];
            float4 blo = *(const float4*)&Bs[k * 132 + n0];
            float4 bhi = *(const float4*)&Bs[k * 132 + n0 + 64];
            #pragma unroll
            for (int i = 0; i < 4; ++i) {
                float a = ((const float*)&av)[i];
                acc[i][0] = fmaf(a, blo.x, acc[i][0]);
                acc[i][1] = fmaf(a, blo.y, acc[i][1]);
                acc[i][2] = fmaf(a, blo.z, acc[i][2]);
                acc[i][3] = fmaf(a, blo.w, acc[i][3]);
                acc[i][4] = fmaf(a, bhi.x, acc[i][4]);
                acc[i][5] = fmaf(a, bhi.y, acc[i][5]);
                acc[i][6] = fmaf(a, bhi.z, acc[i][6]);
                acc[i][7] = fmaf(a, bhi.w, acc[i][7]);
            }
        }
    }
    int hg = mt * 64 + m0;
    int ng = nt * 128;
    #pragma unroll
    for (int j = 0; j < 8; ++j) {
        int n = ng + ((j < 4) ? (n0 + j) : (64 + n0 + j - 4));
        float bias = b2[n];
        float4 v = { acc[0][j] + bias, acc[1][j] + bias, acc[2][j] + bias, acc[3][j] + bias };
        *(float4*)(y2 + ((size_t)b * N_ + n) * H_ + hg) = v;
    }
}

// ---------------- fused LN2 + channel MLP ----------------
// 64 rows/block; yt swizzled in LDS; 16 hidden chunks of 32
__global__ __launch_bounds__(256, 2)
void k_chmlp(const float* __restrict__ y2, const float* __restrict__ lng,
             const float* __restrict__ lnb, const float* __restrict__ w1g,
             const float* __restrict__ b1g, const float* __restrict__ w2g,
             const float* __restrict__ b2g, float* __restrict__ out) {
    __shared__ float yt[64 * 128];      // swizzled: word = r*128 + 4*((c>>2)^swz(r)) + (c&3)
    __shared__ float w1c[128 * 36];     // [k(H)][j(32 hid)] padded
    __shared__ float w2c[32 * 132];     // [k(hid)][o(H)] padded
    __shared__ float ht[64 * 32];       // swizzled: word = r*32 + 4*((h>>2)^((r>>2)&7)) + (h&3)

    int tid = threadIdx.x;
    size_t r0g = (size_t)blockIdx.x * 64;

    // stage y2 tile (swizzled)
    #pragma unroll
    for (int i = 0; i < 8; ++i) {
        int idx = tid + i * 256;
        int r = idx >> 5, c4 = idx & 31;
        float4 v = *(const float4*)(y2 + (r0g + r) * H_ + c4 * 4);
        int sw = ((r >> 2) & 7) | ((r & 3) << 3);
        *(float4*)&yt[r * 128 + 4 * (c4 ^ sw)] = v;
    }
    __syncthreads();

    // LN2 in LDS: wave w handles rows w*16 .. w*16+15
    {
        int wave = tid >> 6, lane = tid & 63;
        float g_lo = lng[lane], g_hi = lng[lane + 64];
        float b_lo = lnb[lane], b_hi = lnb[lane + 64];
        for (int rr = 0; rr < 16; ++rr) {
            int r = wave * 16 + rr;
            int sw = ((r >> 2) & 7) | ((r & 3) << 3);
            int i_lo = r * 128 + 4 * ((lane >> 2) ^ sw) + (lane & 3);
            int c2 = lane + 64;
            int i_hi = r * 128 + 4 * ((c2 >> 2) ^ sw) + (c2 & 3);
            float a = yt[i_lo], c = yt[i_hi];
            float s = a + c, ss = a * a + c * c;
            #pragma unroll
            for (int off = 32; off > 0; off >>= 1) {
                s += __shfl_xor(s, off);
                ss += __shfl_xor(ss, off);
            }
            float mean = s * (1.f / 128.f);
            float var = ss * (1.f / 128.f) - mean * mean;
            float rstd = rsqrtf(var + 1e-5f);
            yt[i_lo] = (a - mean) * rstd * g_lo + b_lo;
            yt[i_hi] = (c - mean) * rstd * g_hi + b_hi;
        }
    }

    int tx = tid & 15, ty = tid >> 4;
    int r0 = ty * 4, h0 = tx * 2, o0 = tx * 4;
    float oa[4][8] = {};

    for (int hc = 0; hc < 16; ++hc) {
        int c0 = hc * 32;
        __syncthreads();
        // stage w1 chunk [128][32]
        #pragma unroll
        for (int i = 0; i < 4; ++i) {
            int idx = tid + i * 256;
            int r = idx >> 3, c4 = idx & 7;
            float4 v = *(const float4*)(w1g + (size_t)r * C_ + c0 + c4 * 4);
            *(float4*)&w1c[r * 36 + c4 * 4] = v;
        }
        // stage w2 chunk [32][128]
        #pragma unroll
        for (int i = 0; i < 4; ++i) {
            int idx = tid + i * 256;
            int r = idx >> 5, c4 = idx & 31;
            float4 v = *(const float4*)(w2g + (size_t)(c0 + r) * H_ + c4 * 4);
            *(float4*)&w2c[r * 132 + c4 * 4] = v;
        }
        __syncthreads();

        // phase 1: h = gelu(y @ w1chunk + b1chunk), 4 rows x 2 hid per thread
        {
            float b1a = b1g[c0 + h0], b1b = b1g[c0 + h0 + 1];
            float ha[4][2];
            #pragma unroll
            for (int i = 0; i < 4; ++i) { ha[i][0] = b1a; ha[i][1] = b1b; }
            #pragma unroll 4
            for (int k = 0; k < 128; k += 4) {
                float4 yv[4];
                #pragma unroll
                for (int i = 0; i < 4; ++i) {
                    int r = r0 + i;
                    int sw = ((r >> 2) & 7) | ((r & 3) << 3);
                    yv[i] = *(const float4*)&yt[r * 128 + 4 * ((k >> 2) ^ sw)];
                }
                #pragma unroll
                for (int kk = 0; kk < 4; ++kk) {
                    float2 wv = *(const float2*)&w1c[(k + kk) * 36 + h0];
                    #pragma unroll
                    for (int i = 0; i < 4; ++i) {
                        float yv_ = ((const float*)&yv[i])[kk];
                        ha[i][0] = fmaf(yv_, wv.x, ha[i][0]);
                        ha[i][1] = fmaf(yv_, wv.y, ha[i][1]);
                    }
                }
            }
            #pragma unroll
            for (int i = 0; i < 4; ++i) {
                int r = r0 + i;
                int swh = (r >> 2) & 7;
                #pragma unroll
                for (int j = 0; j < 2; ++j) {
                    int h = h0 + j;
                    ht[r * 32 + 4 * ((h >> 2) ^ swh) + (h & 3)] = gelu_f(ha[i][j]);
                }
            }
        }
        __syncthreads();

        // phase 2: out += h @ w2chunk, 4 rows x 8 out per thread
        #pragma unroll 2
        for (int k = 0; k < 32; k += 4) {
            float4 hv[4];
            #pragma unroll
            for (int i = 0; i < 4; ++i) {
                int r = r0 + i;
                hv[i] = *(const float4*)&ht[r * 32 + 4 * ((k >> 2) ^ ((r >> 2) & 7))];
            }
            #pragma unroll
            for (int kk = 0; kk < 4; ++kk) {
                float4 wlo = *(const float4*)&w2c[(k + kk) * 132 + o0];
                float4 whi = *(const float4*)&w2c[(k + kk) * 132 + o0 + 64];
                #pragma unroll
                for (int i = 0; i < 4; ++i) {
                    float h = ((const float*)&hv[i])[kk];
                    oa[i][0] = fmaf(h, wlo.x, oa[i][0]);
                    oa[i][1] = fmaf(h, wlo.y, oa[i][1]);
                    oa[i][2] = fmaf(h, wlo.z, oa[i][2]);
                    oa[i][3] = fmaf(h, wlo.w, oa[i][3]);
                    oa[i][4] = fmaf(h, whi.x, oa[i][4]);
                    oa[i][5] = fmaf(h, whi.y, oa[i][5]);
                    oa[i][6] = fmaf(h, whi.z, oa[i][6]);
                    oa[i][7] = fmaf(h, whi.w, oa[i][7]);
                }
            }
        }
    }

    // epilogue: + ch_b2, store
    float4 blo = *(const float4*)(b2g + o0);
    float4 bhi = *(const float4*)(b2g + o0 + 64);
    #pragma unroll
    for (int i = 0; i < 4; ++i) {
        size_t row = r0g + r0 + i;
        float4 v0 = { oa[i][0] + blo.x, oa[i][1] + blo.y, oa[i][2] + blo.z, oa[i][3] + blo.w };
        float4 v1 = { oa[i][4] + bhi.x, oa[i][5] + bhi.y, oa[i][6] + bhi.z, oa[i][7] + bhi.w };
        *(float4*)(out + row * H_ + o0)      = v0;
        *(float4*)(out + row * H_ + o0 + 64) = v1;
    }
}

extern "C" void kernel_launch(void* const* d_in, const int* in_sizes, int n_in,
                              void* d_out, int out_size, void* d_ws, size_t ws_size,
                              hipStream_t stream) {
    const float* x      = (const float*)d_in[0];
    const float* ln1_g  = (const float*)d_in[1];
    const float* ln1_b  = (const float*)d_in[2];
    const float* ln2_g  = (const float*)d_in[3];
    const float* ln2_b  = (const float*)d_in[4];
    const float* tok_w1 = (const float*)d_in[5];
    const float* tok_b1 = (const float*)d_in[6];
    const float* tok_w2 = (const float*)d_in[7];
    const float* tok_b2 = (const float*)d_in[8];
    const float* ch_w1  = (const float*)d_in[9];
    const float* ch_b1  = (const float*)d_in[10];
    const float* ch_w2  = (const float*)d_in[11];
    const float* ch_b2  = (const float*)d_in[12];
    float* out = (float*)d_out;
    float* ws  = (float*)d_ws;

    float* w1c  = ws;                         // 2,097,152
    float* psum = w1c + 2097152;              // 32,768
    float* offs = psum + 32768;               // 32,768
    float* y1   = offs + 32768;               // 16,777,216 (reused as y2)
    float* g1   = y1 + 16777216;              // 524,288
    float* g1p  = g1 + 524288;                // 4,194,304

    k_w1_psum<<<dim3(128), dim3(256), 0, stream>>>(tok_w1, psum);
    k_w1_scan<<<dim3(1), dim3(256), 0, stream>>>(psum, offs);
    k_w1_prefix<<<dim3(128), dim3(256), 0, stream>>>(tok_w1, offs, w1c);
    k_ln<<<dim3((B_ * N_) / 4), dim3(256), 0, stream>>>(x, ln1_g, ln1_b, y1);
    k_tok1<<<dim3(2, 2, B_ * 8), dim3(256), 0, stream>>>(y1, w1c, g1p);
    k_tok1_fin<<<dim3((B_ * H_ * T_) / 1024), dim3(256), 0, stream>>>(g1p, tok_b1, g1);
    k_tok2<<<dim3(64, 2, B_), dim3(256), 0, stream>>>(g1, tok_w2, tok_b2, y1);
    k_chmlp<<<dim3((B_ * N_) / 64), dim3(256), 0, stream>>>(y1, ln2_g, ln2_b,
                                                            ch_w1, ch_b1, ch_w2, ch_b2, out);
}

// Round 2
// 343.540 us; speedup vs baseline: 2.3656x; 2.3656x over previous
//
#include <hip/hip_runtime.h>
#include <math.h>

#define B_ 16
#define N_ 8192
#define H_ 128
#define T_ 256   // TOK_MLP
#define C_ 512   // CH_MLP

typedef __bf16 bf16x8 __attribute__((ext_vector_type(8)));
typedef float f32x4 __attribute__((ext_vector_type(4)));

__device__ __forceinline__ float gelu_f(float x) {
    return 0.5f * x * (1.0f + erff(x * 0.70710678118654752f));
}

__device__ __forceinline__ unsigned short f2bf(float x) {
    unsigned int u = __float_as_uint(x);
    u = (u + 0x7FFFu + ((u >> 16) & 1u)) >> 16;
    return (unsigned short)u;
}

__device__ __forceinline__ void gl2lds16(const void* g, void* l) {
    __builtin_amdgcn_global_load_lds(
        (const __attribute__((address_space(1))) void*)g,
        (__attribute__((address_space(3))) void*)l,
        16, 0, 0);
}

// ---------------- tok_w1 prefix cumsum (3 tiny kernels) ----------------
__global__ void k_w1_psum(const float* __restrict__ w1, float* __restrict__ psum) {
    int c = blockIdx.x, t = threadIdx.x;
    const float* p = w1 + (size_t)c * 64 * T_ + t;
    float s = 0.f;
    #pragma unroll 8
    for (int r = 0; r < 64; ++r) s += p[(size_t)r * T_];
    psum[c * T_ + t] = s;
}

__global__ void k_w1_scan(const float* __restrict__ psum, float* __restrict__ offs) {
    int t = threadIdx.x;
    float run = 0.f;
    for (int c = 0; c < 128; ++c) {
        offs[c * T_ + t] = run;
        run += psum[c * T_ + t];
    }
}

__global__ void k_w1_prefix(const float* __restrict__ w1, const float* __restrict__ offs,
                            float* __restrict__ w1c) {
    int c = blockIdx.x, t = threadIdx.x;
    float run = offs[c * T_ + t];
    const float* p = w1 + (size_t)c * 64 * T_ + t;
    float* q = w1c + (size_t)c * 64 * T_ + t;
    for (int r = 0; r < 64; ++r) { run += p[(size_t)r * T_]; q[(size_t)r * T_] = run; }
}

// ---------------- weight prepack: transpose + bf16 + chunk-swizzled image ----------------
// w1p: 8 chunks of [64 n(hid)][128 k(H)] bf16, byte ^= ((n&7)<<4) within row
__global__ void k_pack1(const float* __restrict__ w1, unsigned short* __restrict__ w1p) {
    int e = blockIdx.x * 256 + threadIdx.x;      // 0..65535
    int c = e >> 13, t = e & 8191;
    int n = t >> 7, j = t & 127;
    int k = j ^ ((n & 7) << 3);                  // element-granular inverse swizzle
    int hid = c * 64 + n;
    w1p[e] = f2bf(w1[(size_t)k * C_ + hid]);
}

// w2p: 8 chunks of [128 n(ch)][64 k(hid)] bf16, byte ^= ((n&7)<<4) within row
__global__ void k_pack2(const float* __restrict__ w2, unsigned short* __restrict__ w2p) {
    int e = blockIdx.x * 256 + threadIdx.x;      // 0..65535
    int c = e >> 13, t = e & 8191;
    int n = t >> 6, j = t & 63;
    int k = j ^ ((n & 7) << 3);
    w2p[e] = f2bf(w2[(size_t)(c * 64 + k) * H_ + n]);
}

// ---------------- LayerNorm over H=128 (wave per row) -> f32 out ----------------
__global__ void k_ln(const float* __restrict__ x, const float* __restrict__ g,
                     const float* __restrict__ bb, float* __restrict__ y) {
    int wave = threadIdx.x >> 6, lane = threadIdx.x & 63;
    size_t row = (size_t)blockIdx.x * 4 + wave;
    const float* xr = x + row * H_;
    float2 v = *(const float2*)(xr + lane * 2);
    float s = v.x + v.y, ss = v.x * v.x + v.y * v.y;
    #pragma unroll
    for (int off = 32; off > 0; off >>= 1) {
        s += __shfl_xor(s, off);
        ss += __shfl_xor(ss, off);
    }
    float mean = s * (1.f / 128.f);
    float var = ss * (1.f / 128.f) - mean * mean;
    float rstd = rsqrtf(var + 1e-5f);
    float2 gg = *(const float2*)(g + lane * 2);
    float2 bv = *(const float2*)(bb + lane * 2);
    float2 o;
    o.x = (v.x - mean) * rstd * gg.x + bv.x;
    o.y = (v.y - mean) * rstd * gg.y + bv.y;
    *(float2*)(y + row * H_ + lane * 2) = o;
}

// ---------------- LN2 -> bf16 pre-swizzled tile image ----------------
// y2p tile t (128 rows): byte = t*32768 + rr*256 + ((col*2) ^ ((rr&7)<<4))
__global__ void k_ln2(const float* __restrict__ y, const float* __restrict__ g,
                      const float* __restrict__ bb, unsigned short* __restrict__ yp) {
    int wave = threadIdx.x >> 6, lane = threadIdx.x & 63;
    size_t row = (size_t)blockIdx.x * 4 + wave;
    const float* xr = y + row * H_;
    float2 v = *(const float2*)(xr + lane * 2);
    float s = v.x + v.y, ss = v.x * v.x + v.y * v.y;
    #pragma unroll
    for (int off = 32; off > 0; off >>= 1) {
        s += __shfl_xor(s, off);
        ss += __shfl_xor(ss, off);
    }
    float mean = s * (1.f / 128.f);
    float var = ss * (1.f / 128.f) - mean * mean;
    float rstd = rsqrtf(var + 1e-5f);
    float2 gg = *(const float2*)(g + lane * 2);
    float2 bv = *(const float2*)(bb + lane * 2);
    float o0 = (v.x - mean) * rstd * gg.x + bv.x;
    float o1 = (v.y - mean) * rstd * gg.y + bv.y;
    unsigned int pk = (unsigned int)f2bf(o0) | ((unsigned int)f2bf(o1) << 16);
    size_t tile = row >> 7;
    int rr = (int)(row & 127);
    *(unsigned int*)((char*)yp + tile * 32768 + rr * 256 + ((lane * 4) ^ ((rr & 7) << 4))) = pk;
}

// ---------------- token GEMM1 (f32, split-K 8) ----------------
__global__ void k_tok1(const float* __restrict__ y1, const float* __restrict__ w1c_g,
                       float* __restrict__ g1p) {
    int nt = blockIdx.x;
    int mt = blockIdx.y;
    int bz = blockIdx.z;            // b*8 + kk
    int b  = bz >> 3, kk = bz & 7;
    const float* A  = y1 + (size_t)b * N_ * H_ + (size_t)mt * 64;
    const float* Bg = w1c_g + nt * 128;
    int kbase = kk * (N_ / 8);

    __shared__ float As[32 * 68];
    __shared__ float Bs[32 * 132];
    int tid = threadIdx.x;
    int tx = tid & 15, ty = tid >> 4;
    int m0 = tx * 4, n0 = ty * 4;
    float acc[4][8] = {};

    for (int k0 = kbase; k0 < kbase + N_ / 8; k0 += 32) {
        __syncthreads();
        #pragma unroll
        for (int i = 0; i < 2; ++i) {
            int idx = tid + i * 256;
            int r = idx >> 4, c4 = idx & 15;
            float4 v = *(const float4*)(A + (size_t)(k0 + r) * H_ + c4 * 4);
            *(float4*)&As[r * 68 + c4 * 4] = v;
        }
        #pragma unroll
        for (int i = 0; i < 4; ++i) {
            int idx = tid + i * 256;
            int r = idx >> 5, c4 = idx & 31;
            float4 v = *(const float4*)(Bg + (size_t)(k0 + r) * T_ + c4 * 4);
            *(float4*)&Bs[r * 132 + c4 * 4] = v;
        }
        __syncthreads();
        #pragma unroll 4
        for (int k = 0; k < 32; ++k) {
            float4 av  = *(const float4*)&As[k * 68 + m0];
            float4 blo = *(const float4*)&Bs[k * 132 + n0];
            float4 bhi = *(const float4*)&Bs[k * 132 + n0 + 64];
            #pragma unroll
            for (int i = 0; i < 4; ++i) {
                float a = ((const float*)&av)[i];
                acc[i][0] = fmaf(a, blo.x, acc[i][0]);
                acc[i][1] = fmaf(a, blo.y, acc[i][1]);
                acc[i][2] = fmaf(a, blo.z, acc[i][2]);
                acc[i][3] = fmaf(a, blo.w, acc[i][3]);
                acc[i][4] = fmaf(a, bhi.x, acc[i][4]);
                acc[i][5] = fmaf(a, bhi.y, acc[i][5]);
                acc[i][6] = fmaf(a, bhi.z, acc[i][6]);
                acc[i][7] = fmaf(a, bhi.w, acc[i][7]);
            }
        }
    }
    float* P = g1p + ((size_t)kk * B_ + b) * H_ * T_;
    int hg = mt * 64 + m0;
    int tg = nt * 128 + n0;
    #pragma unroll
    for (int i = 0; i < 4; ++i) {
        float4 v0 = { acc[i][0], acc[i][1], acc[i][2], acc[i][3] };
        float4 v1 = { acc[i][4], acc[i][5], acc[i][6], acc[i][7] };
        *(float4*)(P + (size_t)(hg + i) * T_ + tg)      = v0;
        *(float4*)(P + (size_t)(hg + i) * T_ + tg + 64) = v1;
    }
}

__global__ void k_tok1_fin(const float* __restrict__ g1p, const float* __restrict__ b1,
                           float* __restrict__ g1) {
    size_t fid = (size_t)blockIdx.x * 256 + threadIdx.x;
    size_t base = fid * 4;
    const size_t S = (size_t)B_ * H_ * T_;
    float4 a = *(const float4*)(g1p + base);
    #pragma unroll
    for (int kk = 1; kk < 8; ++kk) {
        float4 p = *(const float4*)(g1p + (size_t)kk * S + base);
        a.x += p.x; a.y += p.y; a.z += p.z; a.w += p.w;
    }
    int t = (int)(base & (T_ - 1));
    float4 bb = *(const float4*)(b1 + t);
    float4 o;
    o.x = gelu_f(a.x + bb.x);
    o.y = gelu_f(a.y + bb.y);
    o.z = gelu_f(a.z + bb.z);
    o.w = gelu_f(a.w + bb.w);
    *(float4*)(g1 + base) = o;
}

// ---------------- token GEMM2 (f32, transposed store) ----------------
__global__ void k_tok2(const float* __restrict__ g1, const float* __restrict__ w2,
                       const float* __restrict__ b2, float* __restrict__ y2) {
    int nt = blockIdx.x;
    int mt = blockIdx.y;
    int b  = blockIdx.z;
    const float* A  = g1 + (size_t)b * H_ * T_ + (size_t)mt * 64 * T_;
    const float* Bg = w2 + (size_t)nt * 128;

    __shared__ float As[32 * 68];
    __shared__ float Bs[32 * 132];
    int tid = threadIdx.x;
    int tx = tid & 15, ty = tid >> 4;
    int m0 = tx * 4, n0 = ty * 4;
    float acc[4][8] = {};

    for (int k0 = 0; k0 < T_; k0 += 32) {
        __syncthreads();
        #pragma unroll
        for (int i = 0; i < 2; ++i) {
            int idx = tid + i * 256;
            int m = idx >> 3, kq = idx & 7;
            float4 v = *(const float4*)(A + (size_t)m * T_ + k0 + kq * 4);
            As[(kq * 4 + 0) * 68 + m] = v.x;
            As[(kq * 4 + 1) * 68 + m] = v.y;
            As[(kq * 4 + 2) * 68 + m] = v.z;
            As[(kq * 4 + 3) * 68 + m] = v.w;
        }
        #pragma unroll
        for (int i = 0; i < 4; ++i) {
            int idx = tid + i * 256;
            int r = idx >> 5, c4 = idx & 31;
            float4 v = *(const float4*)(Bg + (size_t)(k0 + r) * N_ + c4 * 4);
            *(float4*)&Bs[r * 132 + c4 * 4] = v;
        }
        __syncthreads();
        #pragma unroll 4
        for (int k = 0; k < 32; ++k) {
            float4 av  = *(const float4*)&As[k * 68 + m0];
            float4 blo = *(const float4*)&Bs[k * 132 + n0];
            float4 bhi = *(const float4*)&Bs[k * 132 + n0 + 64];
            #pragma unroll
            for (int i = 0; i < 4; ++i) {
                float a = ((const float*)&av)[i];
                acc[i][0] = fmaf(a, blo.x, acc[i][0]);
                acc[i][1] = fmaf(a, blo.y, acc[i][1]);
                acc[i][2] = fmaf(a, blo.z, acc[i][2]);
                acc[i][3] = fmaf(a, blo.w, acc[i][3]);
                acc[i][4] = fmaf(a, bhi.x, acc[i][4]);
                acc[i][5] = fmaf(a, bhi.y, acc[i][5]);
                acc[i][6] = fmaf(a, bhi.z, acc[i][6]);
                acc[i][7] = fmaf(a, bhi.w, acc[i][7]);
            }
        }
    }
    int hg = mt * 64 + m0;
    int ng = nt * 128;
    #pragma unroll
    for (int j = 0; j < 8; ++j) {
        int n = ng + ((j < 4) ? (n0 + j) : (64 + n0 + j - 4));
        float bias = b2[n];
        float4 v = { acc[0][j] + bias, acc[1][j] + bias, acc[2][j] + bias, acc[3][j] + bias };
        *(float4*)(y2 + ((size_t)b * N_ + n) * H_ + hg) = v;
    }
}

// ---------------- fused LN2-consumer channel MLP via bf16 MFMA ----------------
// 128-token tile, 8 waves, 8 hidden chunks of 64.
// LDS: ys 32KB | hs 16KB | w1c 16KB | w2c 16KB = 80KB -> 2 blocks/CU
#define LDS_YS 0
#define LDS_HS 32768
#define LDS_W1 49152
#define LDS_W2 65536

__global__ __launch_bounds__(512, 4)
void k_chmlp2(const unsigned short* __restrict__ y2p, const unsigned short* __restrict__ w1p,
              const unsigned short* __restrict__ w2p, const float* __restrict__ b1g,
              const float* __restrict__ b2g, float* __restrict__ out) {
    __shared__ __align__(16) char sm[81920];
    int tid = threadIdx.x;
    int w = tid >> 6, lane = tid & 63;
    int tile = blockIdx.x;
    const char* ybase = (const char*)y2p + (size_t)tile * 32768;
    const char* w1b = (const char*)w1p;
    const char* w2b = (const char*)w2p;

    // stage y tile + chunk-0 weights (linear dest; images pre-swizzled)
    #pragma unroll
    for (int j = 0; j < 4; ++j)
        gl2lds16(ybase + w * 4096 + j * 1024 + lane * 16, sm + LDS_YS + w * 4096 + j * 1024);
    #pragma unroll
    for (int j = 0; j < 2; ++j) {
        gl2lds16(w1b + w * 2048 + j * 1024 + lane * 16, sm + LDS_W1 + w * 2048 + j * 1024);
        gl2lds16(w2b + w * 2048 + j * 1024 + lane * 16, sm + LDS_W2 + w * 2048 + j * 1024);
    }
    __syncthreads();   // drains vmcnt(0) before barrier

    int mg = w >> 1, ng = w & 1;          // 4 m-groups x 2 n-groups
    int lr = lane & 15, lk = lane >> 4;   // frag row/col, k-group
    int key = (lr & 7) << 4;              // swizzle key for frag reads (row = *16 + lr)

    f32x4 oacc[2][4];
    #pragma unroll
    for (int m = 0; m < 2; ++m)
        #pragma unroll
        for (int n = 0; n < 4; ++n) oacc[m][n] = (f32x4){0.f, 0.f, 0.f, 0.f};

    for (int c = 0; c < 8; ++c) {
        // ---- GEMM1: h[2m][2n] = ys(tok,128H) @ w1c(64hid,128H^T), K=128
        f32x4 hacc[2][2];
        #pragma unroll
        for (int n = 0; n < 2; ++n) {
            float bv = b1g[c * 64 + (2 * ng + n) * 16 + lr];
            hacc[0][n] = (f32x4){bv, bv, bv, bv};
            hacc[1][n] = hacc[0][n];
        }
        #pragma unroll
        for (int kc = 0; kc < 4; ++kc) {
            int ko = kc * 64 + lk * 16;
            bf16x8 a0 = *(const bf16x8*)(sm + LDS_YS + ((2 * mg) * 16 + lr) * 256 + (ko ^ key));
            bf16x8 a1 = *(const bf16x8*)(sm + LDS_YS + ((2 * mg + 1) * 16 + lr) * 256 + (ko ^ key));
            bf16x8 b0 = *(const bf16x8*)(sm + LDS_W1 + ((2 * ng) * 16 + lr) * 256 + (ko ^ key));
            bf16x8 b1 = *(const bf16x8*)(sm + LDS_W1 + ((2 * ng + 1) * 16 + lr) * 256 + (ko ^ key));
            hacc[0][0] = __builtin_amdgcn_mfma_f32_16x16x32_bf16(a0, b0, hacc[0][0], 0, 0, 0);
            hacc[0][1] = __builtin_amdgcn_mfma_f32_16x16x32_bf16(a0, b1, hacc[0][1], 0, 0, 0);
            hacc[1][0] = __builtin_amdgcn_mfma_f32_16x16x32_bf16(a1, b0, hacc[1][0], 0, 0, 0);
            hacc[1][1] = __builtin_amdgcn_mfma_f32_16x16x32_bf16(a1, b1, hacc[1][1], 0, 0, 0);
        }
        // gelu -> hs (bf16, swizzled rows of 128B)
        #pragma unroll
        for (int m = 0; m < 2; ++m)
            #pragma unroll
            for (int n = 0; n < 2; ++n)
                #pragma unroll
                for (int r = 0; r < 4; ++r) {
                    int tok = (2 * mg + m) * 16 + lk * 4 + r;
                    int hid = (2 * ng + n) * 16 + lr;
                    float gval = gelu_f(hacc[m][n][r]);
                    *(unsigned short*)(sm + LDS_HS + tok * 128 + ((hid * 2) ^ ((tok & 7) << 4))) = f2bf(gval);
                }
        __syncthreads();
        if (c < 7) {   // prefetch next w1 chunk (overlaps GEMM2)
            #pragma unroll
            for (int j = 0; j < 2; ++j)
                gl2lds16(w1b + (c + 1) * 16384 + w * 2048 + j * 1024 + lane * 16,
                         sm + LDS_W1 + w * 2048 + j * 1024);
        }
        // ---- GEMM2: out[2m][4n] += hs(tok,64hid) @ w2c(128ch,64hid^T), K=64
        #pragma unroll
        for (int kc = 0; kc < 2; ++kc) {
            int ko = kc * 64 + lk * 16;
            bf16x8 a0 = *(const bf16x8*)(sm + LDS_HS + ((2 * mg) * 16 + lr) * 128 + (ko ^ key));
            bf16x8 a1 = *(const bf16x8*)(sm + LDS_HS + ((2 * mg + 1) * 16 + lr) * 128 + (ko ^ key));
            #pragma unroll
            for (int n = 0; n < 4; ++n) {
                bf16x8 bb = *(const bf16x8*)(sm + LDS_W2 + ((ng * 4 + n) * 16 + lr) * 128 + (ko ^ key));
                oacc[0][n] = __builtin_amdgcn_mfma_f32_16x16x32_bf16(a0, bb, oacc[0][n], 0, 0, 0);
                oacc[1][n] = __builtin_amdgcn_mfma_f32_16x16x32_bf16(a1, bb, oacc[1][n], 0, 0, 0);
            }
        }
        __syncthreads();
        if (c < 7) {   // prefetch next w2 chunk (overlaps next GEMM1)
            #pragma unroll
            for (int j = 0; j < 2; ++j)
                gl2lds16(w2b + (c + 1) * 16384 + w * 2048 + j * 1024 + lane * 16,
                         sm + LDS_W2 + w * 2048 + j * 1024);
        }
    }

    // epilogue: + ch_b2, f32 store
    #pragma unroll
    for (int n = 0; n < 4; ++n) {
        int ch = (ng * 4 + n) * 16 + lr;
        float bv = b2g[ch];
        #pragma unroll
        for (int m = 0; m < 2; ++m)
            #pragma unroll
            for (int r = 0; r < 4; ++r) {
                size_t row = (size_t)tile * 128 + (2 * mg + m) * 16 + lk * 4 + r;
                out[row * H_ + ch] = oacc[m][n][r] + bv;
            }
    }
}

extern "C" void kernel_launch(void* const* d_in, const int* in_sizes, int n_in,
                              void* d_out, int out_size, void* d_ws, size_t ws_size,
                              hipStream_t stream) {
    const float* x      = (const float*)d_in[0];
    const float* ln1_g  = (const float*)d_in[1];
    const float* ln1_b  = (const float*)d_in[2];
    const float* ln2_g  = (const float*)d_in[3];
    const float* ln2_b  = (const float*)d_in[4];
    const float* tok_w1 = (const float*)d_in[5];
    const float* tok_b1 = (const float*)d_in[6];
    const float* tok_w2 = (const float*)d_in[7];
    const float* tok_b2 = (const float*)d_in[8];
    const float* ch_w1  = (const float*)d_in[9];
    const float* ch_b1  = (const float*)d_in[10];
    const float* ch_w2  = (const float*)d_in[11];
    const float* ch_b2  = (const float*)d_in[12];
    float* out = (float*)d_out;
    float* ws  = (float*)d_ws;

    float* w1c  = ws;                            // 2,097,152 f
    float* psum = ws + 2097152;                  //    32,768 f
    float* offs = ws + 2129920;                  //    32,768 f
    float* y1   = ws + 2162688;                  // 16,777,216 f (reused as y2)
    float* g1   = ws + 18939904;                 //   524,288 f   (dead after k_tok2)
    float* g1p  = ws + 19464192;                 // 4,194,304 f   (dead after k_tok1_fin)
    unsigned short* y2p = (unsigned short*)(ws + 18939904);   // 32 MB, overlays g1/g1p (temporal)
    unsigned short* w1p = (unsigned short*)(ws + 27328512);   // 128 KB
    unsigned short* w2p = (unsigned short*)(ws + 27361280);   // 128 KB
    // total ws use: 27,394,048 floats = 109.6 MB

    k_w1_psum<<<dim3(128), dim3(256), 0, stream>>>(tok_w1, psum);
    k_w1_scan<<<dim3(1), dim3(256), 0, stream>>>(psum, offs);
    k_w1_prefix<<<dim3(128), dim3(256), 0, stream>>>(tok_w1, offs, w1c);
    k_pack1<<<dim3(256), dim3(256), 0, stream>>>(ch_w1, w1p);
    k_pack2<<<dim3(256), dim3(256), 0, stream>>>(ch_w2, w2p);
    k_ln<<<dim3((B_ * N_) / 4), dim3(256), 0, stream>>>(x, ln1_g, ln1_b, y1);
    k_tok1<<<dim3(2, 2, B_ * 8), dim3(256), 0, stream>>>(y1, w1c, g1p);
    k_tok1_fin<<<dim3((B_ * H_ * T_) / 1024), dim3(256), 0, stream>>>(g1p, tok_b1, g1);
    k_tok2<<<dim3(64, 2, B_), dim3(256), 0, stream>>>(g1, tok_w2, tok_b2, y1);
    k_ln2<<<dim3((B_ * N_) / 4), dim3(256), 0, stream>>>(y1, ln2_g, ln2_b, y2p);
    k_chmlp2<<<dim3((B_ * N_) / 128), dim3(512), 0, stream>>>(y2p, w1p, w2p, ch_b1, ch_b2, out);
}

// Round 3
// 163.581 us; speedup vs baseline: 4.9680x; 2.1001x over previous
//
#include <hip/hip_runtime.h>
#include <math.h>

#define B_ 16
#define N_ 8192
#define H_ 128
#define T_ 256   // TOK_MLP
#define C_ 512   // CH_MLP

typedef __bf16 bf16x8 __attribute__((ext_vector_type(8)));
typedef float f32x4 __attribute__((ext_vector_type(4)));

__device__ __forceinline__ float gelu_f(float x) {
    return 0.5f * x * (1.0f + erff(x * 0.70710678118654752f));
}

__device__ __forceinline__ unsigned short f2bf(float x) {
    unsigned int u = __float_as_uint(x);
    u = (u + 0x7FFFu + ((u >> 16) & 1u)) >> 16;
    return (unsigned short)u;
}

__device__ __forceinline__ void gl2lds16(const void* g, void* l) {
    __builtin_amdgcn_global_load_lds(
        (const __attribute__((address_space(1))) void*)g,
        (__attribute__((address_space(3))) void*)l,
        16, 0, 0);
}

// ---------------- tok_w1 prefix cumsum -> transposed swizzled bf16 w1ct[t][n] ----------------
__global__ void k_w1_psum(const float* __restrict__ w1, float* __restrict__ psum) {
    int c = blockIdx.x, t = threadIdx.x;
    const float* p = w1 + (size_t)c * 64 * T_ + t;
    float s = 0.f;
    #pragma unroll 8
    for (int r = 0; r < 64; ++r) s += p[(size_t)r * T_];
    psum[c * T_ + t] = s;
}

__global__ void k_w1_scan(const float* __restrict__ psum, float* __restrict__ offs) {
    int t = threadIdx.x;
    float run = 0.f;
    for (int c = 0; c < 128; ++c) {
        offs[c * T_ + t] = run;
        run += psum[c * T_ + t];
    }
}

// w1ct row t (16KB): per 64-n chunk c: byte = (t*16384) + c*128 + ((nl*2) ^ ((t&7)<<4))
__global__ void k_w1_prefix(const float* __restrict__ w1, const float* __restrict__ offs,
                            unsigned short* __restrict__ w1ct) {
    int c = blockIdx.x, t = threadIdx.x;     // c: n-chunk 0..127
    float run = offs[c * T_ + t];
    const float* p = w1 + (size_t)c * 64 * T_ + t;
    unsigned int wb[32];
    #pragma unroll
    for (int q = 0; q < 32; ++q) {
        run += p[(size_t)(2 * q) * T_];
        unsigned int lo = f2bf(run);
        run += p[(size_t)(2 * q + 1) * T_];
        wb[q] = lo | ((unsigned int)f2bf(run) << 16);
    }
    char* row = (char*)w1ct + ((size_t)t * N_ + c * 64) * 2;
    int key = (t & 7) << 4;
    #pragma unroll
    for (int pc = 0; pc < 8; ++pc) {
        int4 v = { (int)wb[4*pc], (int)wb[4*pc+1], (int)wb[4*pc+2], (int)wb[4*pc+3] };
        *(int4*)(row + ((pc * 16) ^ key)) = v;
    }
}

// ---------------- tok_w2 transpose -> swizzled bf16 w2t[n][t] (512B rows) ----------------
__global__ void k_w2t_pack(const float* __restrict__ w2, unsigned short* __restrict__ w2t) {
    __shared__ float ld[64 * 68];
    int nt = blockIdx.x, tt = blockIdx.y;   // 128 n-tiles x 4 t-tiles (64x64)
    int n0 = nt * 64, t0 = tt * 64;
    int tid = threadIdx.x;
    #pragma unroll
    for (int rnd = 0; rnd < 4; ++rnd) {
        int idx = tid + rnd * 256;
        int tr = idx >> 4, nc = idx & 15;
        float4 v = *(const float4*)(w2 + (size_t)(t0 + tr) * N_ + n0 + nc * 4);
        *(float4*)&ld[tr * 68 + nc * 4] = v;
    }
    __syncthreads();
    int n = tid >> 2, q = tid & 3;
    int key = (n & 7) << 4;
    unsigned int wb[8];
    #pragma unroll
    for (int j = 0; j < 8; ++j) {
        float a = ld[(q * 16 + 2 * j) * 68 + n];
        float b = ld[(q * 16 + 2 * j + 1) * 68 + n];
        wb[j] = (unsigned int)f2bf(a) | ((unsigned int)f2bf(b) << 16);
    }
    char* row = (char*)w2t + (size_t)(n0 + n) * 512 + t0 * 2;
    int4 v0 = { (int)wb[0], (int)wb[1], (int)wb[2], (int)wb[3] };
    int4 v1 = { (int)wb[4], (int)wb[5], (int)wb[6], (int)wb[7] };
    *(int4*)(row + ((q * 32) ^ key)) = v0;
    *(int4*)(row + ((q * 32 + 16) ^ key)) = v1;
}

// ---------------- ch-weight prepack (unchanged, feeds k_chmlp2) ----------------
__global__ void k_pack1(const float* __restrict__ w1, unsigned short* __restrict__ w1p) {
    int e = blockIdx.x * 256 + threadIdx.x;
    int c = e >> 13, t = e & 8191;
    int n = t >> 7, j = t & 127;
    int k = j ^ ((n & 7) << 3);
    int hid = c * 64 + n;
    w1p[e] = f2bf(w1[(size_t)k * C_ + hid]);
}

__global__ void k_pack2(const float* __restrict__ w2, unsigned short* __restrict__ w2p) {
    int e = blockIdx.x * 256 + threadIdx.x;
    int c = e >> 13, t = e & 8191;
    int n = t >> 6, j = t & 63;
    int k = j ^ ((n & 7) << 3);
    w2p[e] = f2bf(w2[(size_t)(c * 64 + k) * H_ + n]);
}

// ---------------- LN1 + transpose -> y1t[b][h][n] bf16, rows swizzled per 64-n chunk ----------------
__global__ void k_lnT(const float* __restrict__ x, const float* __restrict__ g,
                      const float* __restrict__ bb, unsigned short* __restrict__ y1t) {
    __shared__ float ln[64 * 129];
    int tid = threadIdx.x;
    int wave = tid >> 6, lane = tid & 63;
    size_t base = (size_t)blockIdx.x * 64;
    float2 gg = *(const float2*)(g + lane * 2);
    float2 bv = *(const float2*)(bb + lane * 2);
    for (int rr = 0; rr < 16; ++rr) {
        int r = wave * 16 + rr;
        float2 v = *(const float2*)(x + (base + r) * H_ + lane * 2);
        float s = v.x + v.y, ss = v.x * v.x + v.y * v.y;
        #pragma unroll
        for (int off = 32; off; off >>= 1) { s += __shfl_xor(s, off); ss += __shfl_xor(ss, off); }
        float mean = s * (1.f / 128.f);
        float rstd = rsqrtf(ss * (1.f / 128.f) - mean * mean + 1e-5f);
        ln[r * 129 + lane * 2]     = (v.x - mean) * rstd * gg.x + bv.x;
        ln[r * 129 + lane * 2 + 1] = (v.y - mean) * rstd * gg.y + bv.y;
    }
    __syncthreads();
    int h = tid >> 1, half = tid & 1;
    unsigned int wb[16];
    #pragma unroll
    for (int q = 0; q < 16; ++q) {
        float a = ln[(half * 32 + 2 * q) * 129 + h];
        float b = ln[(half * 32 + 2 * q + 1) * 129 + h];
        wb[q] = (unsigned int)f2bf(a) | ((unsigned int)f2bf(b) << 16);
    }
    int b_ = (int)(base >> 13);
    int n0 = (int)(base & (N_ - 1));
    char* row = (char*)y1t + (((size_t)b_ * H_ + h) * N_ + n0) * 2;
    int key = (h & 7) << 4;
    #pragma unroll
    for (int pc = 0; pc < 4; ++pc) {
        int4 v = { (int)wb[4*pc], (int)wb[4*pc+1], (int)wb[4*pc+2], (int)wb[4*pc+3] };
        *(int4*)(row + ((half * 64 + pc * 16) ^ key)) = v;
    }
}

// ---------------- token GEMM1: bf16 MFMA, split-K 16 -> f32 partials ----------------
#define T1_YS 0        // 16KB: ys[h=128][128B swz]
#define T1_WS 16384    // 32KB: ws[t=256][128B swz]

__global__ __launch_bounds__(512, 1)
void k_tok1(const unsigned short* __restrict__ y1t, const unsigned short* __restrict__ w1ct,
            float* __restrict__ P) {
    __shared__ __align__(16) char sm[49152];
    int kk = blockIdx.x, b = blockIdx.y;
    int tid = threadIdx.x;
    int w = tid >> 6, lane = tid & 63;
    int lr = lane & 15, lk = lane >> 4;
    int mg = w >> 2, ng = w & 3;           // wave tile: 64h x 64t
    const char* yb = (const char*)y1t + (size_t)b * H_ * N_ * 2;
    const char* wbg = (const char*)w1ct;
    int kbase = kk * 512;

    f32x4 acc[4][4];
    #pragma unroll
    for (int i = 0; i < 4; ++i)
        #pragma unroll
        for (int j = 0; j < 4; ++j) acc[i][j] = (f32x4){0.f, 0.f, 0.f, 0.f};

    for (int s = 0; s < 8; ++s) {
        int n0 = kbase + s * 64;
        __syncthreads();
        #pragma unroll
        for (int rnd = 0; rnd < 2; ++rnd) {
            int idx = tid + rnd * 512;
            int hr = idx >> 3, p = idx & 7;
            gl2lds16(yb + ((size_t)hr * N_ + n0) * 2 + p * 16, sm + T1_YS + idx * 16);
        }
        #pragma unroll
        for (int rnd = 0; rnd < 4; ++rnd) {
            int idx = tid + rnd * 512;
            int tr = idx >> 3, p = idx & 7;
            gl2lds16(wbg + ((size_t)tr * N_ + n0) * 2 + p * 16, sm + T1_WS + idx * 16);
        }
        __syncthreads();
        #pragma unroll
        for (int ks = 0; ks < 2; ++ks) {
            bf16x8 af[4], bfr[4];
            #pragma unroll
            for (int i = 0; i < 4; ++i) {
                int h = mg * 64 + i * 16 + lr;
                af[i] = *(const bf16x8*)(sm + T1_YS + h * 128 + ((ks * 64 + lk * 16) ^ ((h & 7) << 4)));
            }
            #pragma unroll
            for (int j = 0; j < 4; ++j) {
                int t = ng * 64 + j * 16 + lr;
                bfr[j] = *(const bf16x8*)(sm + T1_WS + t * 128 + ((ks * 64 + lk * 16) ^ ((t & 7) << 4)));
            }
            #pragma unroll
            for (int i = 0; i < 4; ++i)
                #pragma unroll
                for (int j = 0; j < 4; ++j)
                    acc[i][j] = __builtin_amdgcn_mfma_f32_16x16x32_bf16(af[i], bfr[j], acc[i][j], 0, 0, 0);
        }
    }

    float* Pb = P + ((size_t)(b * 16 + kk)) * (H_ * T_);
    #pragma unroll
    for (int i = 0; i < 4; ++i)
        #pragma unroll
        for (int j = 0; j < 4; ++j) {
            int t = ng * 64 + j * 16 + lr;
            #pragma unroll
            for (int r = 0; r < 4; ++r) {
                int h = mg * 64 + i * 16 + lk * 4 + r;
                Pb[h * T_ + t] = acc[i][j][r];
            }
        }
}

// ---------------- combine partials + bias + gelu -> g1b bf16 [b][h][t] swizzled ----------------
__global__ void k_tok1_fin(const float* __restrict__ P, const float* __restrict__ b1,
                           unsigned short* __restrict__ g1b) {
    int fid = blockIdx.x * 256 + threadIdx.x;
    int base = fid * 4;
    int b = base >> 15, rem = base & 32767;
    int h = rem >> 8, t = rem & 255;
    const float* Pb = P + (size_t)b * 16 * 32768 + rem;
    float4 a = *(const float4*)Pb;
    #pragma unroll
    for (int kk = 1; kk < 16; ++kk) {
        float4 p = *(const float4*)(Pb + (size_t)kk * 32768);
        a.x += p.x; a.y += p.y; a.z += p.z; a.w += p.w;
    }
    float4 bb = *(const float4*)(b1 + t);
    unsigned int lo = (unsigned int)f2bf(gelu_f(a.x + bb.x)) | ((unsigned int)f2bf(gelu_f(a.y + bb.y)) << 16);
    unsigned int hi = (unsigned int)f2bf(gelu_f(a.z + bb.z)) | ((unsigned int)f2bf(gelu_f(a.w + bb.w)) << 16);
    char* row = (char*)g1b + (size_t)(b * H_ + h) * 512;
    uint2 v = { lo, hi };
    *(uint2*)(row + ((t * 2) ^ ((h & 7) << 4))) = v;
}

// ---------------- token GEMM2 + tok_b2 + LN2 + bf16 swizzle-pack -> y2p tiles ----------------
#define T2_AS 0        // 64KB: w2t tile (rows tok, 512B swz)
#define T2_BS 65536    // 64KB: g1b[b]  (rows h,   512B swz)

__global__ __launch_bounds__(512, 1)
void k_tok2ln(const unsigned short* __restrict__ g1b, const unsigned short* __restrict__ w2t,
              const float* __restrict__ tb2, const float* __restrict__ lg,
              const float* __restrict__ lb, unsigned short* __restrict__ y2p) {
    __shared__ __align__(16) char sm[131072];
    int nt = blockIdx.x, b = blockIdx.y;
    int tid = threadIdx.x;
    int w = tid >> 6, lane = tid & 63;
    int lr = lane & 15, lk = lane >> 4;
    const char* ab = (const char*)w2t + (size_t)(nt * 128) * 512;
    const char* gb = (const char*)g1b + (size_t)b * H_ * 512;

    #pragma unroll
    for (int rnd = 0; rnd < 8; ++rnd) {
        int idx = tid + rnd * 512;
        gl2lds16(ab + (size_t)idx * 16, sm + T2_AS + idx * 16);
        gl2lds16(gb + (size_t)idx * 16, sm + T2_BS + idx * 16);
    }
    __syncthreads();

    f32x4 acc[8];
    #pragma unroll
    for (int g = 0; g < 8; ++g) acc[g] = (f32x4){0.f, 0.f, 0.f, 0.f};
    int arow = w * 16 + lr;
    const char* aptr = sm + T2_AS + arow * 512;
    int akey = (arow & 7) << 4;
    #pragma unroll
    for (int ks = 0; ks < 8; ++ks) {
        bf16x8 af = *(const bf16x8*)(aptr + ((ks * 64 + lk * 16) ^ akey));
        #pragma unroll
        for (int g = 0; g < 8; ++g) {
            int hrow = g * 16 + lr;
            bf16x8 bf_ = *(const bf16x8*)(sm + T2_BS + hrow * 512 + ((ks * 64 + lk * 16) ^ ((hrow & 7) << 4)));
            acc[g] = __builtin_amdgcn_mfma_f32_16x16x32_bf16(af, bf_, acc[g], 0, 0, 0);
        }
    }

    float gam[8], bet[8];
    #pragma unroll
    for (int g = 0; g < 8; ++g) { gam[g] = lg[g * 16 + lr]; bet[g] = lb[g * 16 + lr]; }
    __syncthreads();   // all waves done reading sm; reuse rows [0,32KB) for y2p tile image

    #pragma unroll
    for (int r = 0; r < 4; ++r) {
        int row = w * 16 + lk * 4 + r;
        float bias2 = tb2[nt * 128 + row];
        float vals[8];
        float s = 0.f, ss = 0.f;
        #pragma unroll
        for (int g = 0; g < 8; ++g) {
            float v = acc[g][r] + bias2;
            vals[g] = v; s += v; ss += v * v;
        }
        #pragma unroll
        for (int off = 8; off; off >>= 1) { s += __shfl_xor(s, off); ss += __shfl_xor(ss, off); }
        float mean = s * (1.f / 128.f);
        float rstd = rsqrtf(ss * (1.f / 128.f) - mean * mean + 1e-5f);
        int key = (row & 7) << 4;
        char* orow = sm + row * 256;
        #pragma unroll
        for (int g = 0; g < 8; ++g) {
            float v = (vals[g] - mean) * rstd * gam[g] + bet[g];
            *(unsigned short*)(orow + (((g * 16 + lr) * 2) ^ key)) = f2bf(v);
        }
    }
    __syncthreads();
    char* dst = (char*)y2p + (size_t)(b * 64 + nt) * 32768;
    #pragma unroll
    for (int rnd = 0; rnd < 4; ++rnd) {
        int idx = tid + rnd * 512;
        *(int4*)(dst + idx * 16) = *(const int4*)(sm + idx * 16);
    }
}

// ---------------- fused channel MLP via bf16 MFMA (unchanged) ----------------
#define LDS_YS 0
#define LDS_HS 32768
#define LDS_W1 49152
#define LDS_W2 65536

__global__ __launch_bounds__(512, 4)
void k_chmlp2(const unsigned short* __restrict__ y2p, const unsigned short* __restrict__ w1p,
              const unsigned short* __restrict__ w2p, const float* __restrict__ b1g,
              const float* __restrict__ b2g, float* __restrict__ out) {
    __shared__ __align__(16) char sm[81920];
    int tid = threadIdx.x;
    int w = tid >> 6, lane = tid & 63;
    int tile = blockIdx.x;
    const char* ybase = (const char*)y2p + (size_t)tile * 32768;
    const char* w1b = (const char*)w1p;
    const char* w2b = (const char*)w2p;

    #pragma unroll
    for (int j = 0; j < 4; ++j)
        gl2lds16(ybase + w * 4096 + j * 1024 + lane * 16, sm + LDS_YS + w * 4096 + j * 1024);
    #pragma unroll
    for (int j = 0; j < 2; ++j) {
        gl2lds16(w1b + w * 2048 + j * 1024 + lane * 16, sm + LDS_W1 + w * 2048 + j * 1024);
        gl2lds16(w2b + w * 2048 + j * 1024 + lane * 16, sm + LDS_W2 + w * 2048 + j * 1024);
    }
    __syncthreads();

    int mg = w >> 1, ng = w & 1;
    int lr = lane & 15, lk = lane >> 4;
    int key = (lr & 7) << 4;

    f32x4 oacc[2][4];
    #pragma unroll
    for (int m = 0; m < 2; ++m)
        #pragma unroll
        for (int n = 0; n < 4; ++n) oacc[m][n] = (f32x4){0.f, 0.f, 0.f, 0.f};

    for (int c = 0; c < 8; ++c) {
        f32x4 hacc[2][2];
        #pragma unroll
        for (int n = 0; n < 2; ++n) {
            float bv = b1g[c * 64 + (2 * ng + n) * 16 + lr];
            hacc[0][n] = (f32x4){bv, bv, bv, bv};
            hacc[1][n] = hacc[0][n];
        }
        #pragma unroll
        for (int kc = 0; kc < 4; ++kc) {
            int ko = kc * 64 + lk * 16;
            bf16x8 a0 = *(const bf16x8*)(sm + LDS_YS + ((2 * mg) * 16 + lr) * 256 + (ko ^ key));
            bf16x8 a1 = *(const bf16x8*)(sm + LDS_YS + ((2 * mg + 1) * 16 + lr) * 256 + (ko ^ key));
            bf16x8 b0 = *(const bf16x8*)(sm + LDS_W1 + ((2 * ng) * 16 + lr) * 256 + (ko ^ key));
            bf16x8 b1 = *(const bf16x8*)(sm + LDS_W1 + ((2 * ng + 1) * 16 + lr) * 256 + (ko ^ key));
            hacc[0][0] = __builtin_amdgcn_mfma_f32_16x16x32_bf16(a0, b0, hacc[0][0], 0, 0, 0);
            hacc[0][1] = __builtin_amdgcn_mfma_f32_16x16x32_bf16(a0, b1, hacc[0][1], 0, 0, 0);
            hacc[1][0] = __builtin_amdgcn_mfma_f32_16x16x32_bf16(a1, b0, hacc[1][0], 0, 0, 0);
            hacc[1][1] = __builtin_amdgcn_mfma_f32_16x16x32_bf16(a1, b1, hacc[1][1], 0, 0, 0);
        }
        #pragma unroll
        for (int m = 0; m < 2; ++m)
            #pragma unroll
            for (int n = 0; n < 2; ++n)
                #pragma unroll
                for (int r = 0; r < 4; ++r) {
                    int tok = (2 * mg + m) * 16 + lk * 4 + r;
                    int hid = (2 * ng + n) * 16 + lr;
                    float gval = gelu_f(hacc[m][n][r]);
                    *(unsigned short*)(sm + LDS_HS + tok * 128 + ((hid * 2) ^ ((tok & 7) << 4))) = f2bf(gval);
                }
        __syncthreads();
        if (c < 7) {
            #pragma unroll
            for (int j = 0; j < 2; ++j)
                gl2lds16(w1b + (c + 1) * 16384 + w * 2048 + j * 1024 + lane * 16,
                         sm + LDS_W1 + w * 2048 + j * 1024);
        }
        #pragma unroll
        for (int kc = 0; kc < 2; ++kc) {
            int ko = kc * 64 + lk * 16;
            bf16x8 a0 = *(const bf16x8*)(sm + LDS_HS + ((2 * mg) * 16 + lr) * 128 + (ko ^ key));
            bf16x8 a1 = *(const bf16x8*)(sm + LDS_HS + ((2 * mg + 1) * 16 + lr) * 128 + (ko ^ key));
            #pragma unroll
            for (int n = 0; n < 4; ++n) {
                bf16x8 bb = *(const bf16x8*)(sm + LDS_W2 + ((ng * 4 + n) * 16 + lr) * 128 + (ko ^ key));
                oacc[0][n] = __builtin_amdgcn_mfma_f32_16x16x32_bf16(a0, bb, oacc[0][n], 0, 0, 0);
                oacc[1][n] = __builtin_amdgcn_mfma_f32_16x16x32_bf16(a1, bb, oacc[1][n], 0, 0, 0);
            }
        }
        __syncthreads();
        if (c < 7) {
            #pragma unroll
            for (int j = 0; j < 2; ++j)
                gl2lds16(w2b + (c + 1) * 16384 + w * 2048 + j * 1024 + lane * 16,
                         sm + LDS_W2 + w * 2048 + j * 1024);
        }
    }

    #pragma unroll
    for (int n = 0; n < 4; ++n) {
        int ch = (ng * 4 + n) * 16 + lr;
        float bv = b2g[ch];
        #pragma unroll
        for (int m = 0; m < 2; ++m)
            #pragma unroll
            for (int r = 0; r < 4; ++r) {
                size_t row = (size_t)tile * 128 + (2 * mg + m) * 16 + lk * 4 + r;
                out[row * H_ + ch] = oacc[m][n][r] + bv;
            }
    }
}

extern "C" void kernel_launch(void* const* d_in, const int* in_sizes, int n_in,
                              void* d_out, int out_size, void* d_ws, size_t ws_size,
                              hipStream_t stream) {
    const float* x      = (const float*)d_in[0];
    const float* ln1_g  = (const float*)d_in[1];
    const float* ln1_b  = (const float*)d_in[2];
    const float* ln2_g  = (const float*)d_in[3];
    const float* ln2_b  = (const float*)d_in[4];
    const float* tok_w1 = (const float*)d_in[5];
    const float* tok_b1 = (const float*)d_in[6];
    const float* tok_w2 = (const float*)d_in[7];
    const float* tok_b2 = (const float*)d_in[8];
    const float* ch_w1  = (const float*)d_in[9];
    const float* ch_b1  = (const float*)d_in[10];
    const float* ch_w2  = (const float*)d_in[11];
    const float* ch_b2  = (const float*)d_in[12];
    float* out = (float*)d_out;
    float* ws  = (float*)d_ws;

    float* psum = ws;                                         //    32,768 f
    float* offs = ws + 32768;                                 //    32,768 f
    unsigned short* w1ct = (unsigned short*)(ws + 65536);     // 2M bf16 (4 MB)
    unsigned short* w2t  = (unsigned short*)(ws + 1114112);   // 2M bf16 (4 MB)
    unsigned short* w1p  = (unsigned short*)(ws + 2162688);   // 64K bf16
    unsigned short* w2p  = (unsigned short*)(ws + 2195456);   // 64K bf16
    unsigned short* y1t  = (unsigned short*)(ws + 2228224);   // 16M bf16 (32 MB)
    unsigned short* g1b  = (unsigned short*)(ws + 10616832);  // 512K bf16 (1 MB)
    float* P             = ws + 10878976;                     // 8M f32 (32 MB)
    unsigned short* y2p  = (unsigned short*)(ws + 10878976);  // overlays P (dead after fin)
    // total: 19,267,584 f32 = 77.1 MB

    k_w1_psum<<<dim3(128), dim3(256), 0, stream>>>(tok_w1, psum);
    k_w1_scan<<<dim3(1), dim3(256), 0, stream>>>(psum, offs);
    k_w1_prefix<<<dim3(128), dim3(256), 0, stream>>>(tok_w1, offs, w1ct);
    k_w2t_pack<<<dim3(128, 4), dim3(256), 0, stream>>>(tok_w2, w2t);
    k_pack1<<<dim3(256), dim3(256), 0, stream>>>(ch_w1, w1p);
    k_pack2<<<dim3(256), dim3(256), 0, stream>>>(ch_w2, w2p);
    k_lnT<<<dim3((B_ * N_) / 64), dim3(256), 0, stream>>>(x, ln1_g, ln1_b, y1t);
    k_tok1<<<dim3(16, 16), dim3(512), 0, stream>>>(y1t, w1ct, P);
    k_tok1_fin<<<dim3(512), dim3(256), 0, stream>>>(P, tok_b1, g1b);
    k_tok2ln<<<dim3(64, 16), dim3(512), 0, stream>>>(g1b, w2t, tok_b2, ln2_g, ln2_b, y2p);
    k_chmlp2<<<dim3((B_ * N_) / 128), dim3(512), 0, stream>>>(y2p, w1p, w2p, ch_b1, ch_b2, out);
}

// Round 4
// 158.636 us; speedup vs baseline: 5.1229x; 1.0312x over previous
//
#include <hip/hip_runtime.h>
#include <math.h>

#define B_ 16
#define N_ 8192
#define H_ 128
#define T_ 256   // TOK_MLP
#define C_ 512   // CH_MLP

typedef __bf16 bf16x8 __attribute__((ext_vector_type(8)));
typedef __bf16 bf16x4 __attribute__((ext_vector_type(4)));
typedef float f32x4 __attribute__((ext_vector_type(4)));

// tanh-form gelu: x * sigmoid(1.5957691(x + 0.044715 x^3)).
// |err| vs erf-gelu < 1.7e-3 (peak at |x|~3); inputs here have sigma 0.23 (chmlp)
// or feed a x0.02-weighted sum + LN (tok path) -> output-level error < 1e-4.
__device__ __forceinline__ float gelu_f(float x) {
    float p = fmaf(0.044715f * x * x, x, x);
    float e = __expf(-1.5957691216057308f * p);
    return x * __builtin_amdgcn_rcpf(1.f + e);
}

__device__ __forceinline__ unsigned short f2bf(float x) {
    unsigned int u = __float_as_uint(x);
    u = (u + 0x7FFFu + ((u >> 16) & 1u)) >> 16;
    return (unsigned short)u;
}

__device__ __forceinline__ void gl2lds16(const void* g, void* l) {
    __builtin_amdgcn_global_load_lds(
        (const __attribute__((address_space(1))) void*)g,
        (__attribute__((address_space(3))) void*)l,
        16, 0, 0);
}

// ---------------- tok_w1 prefix cumsum -> transposed swizzled bf16 w1ct[t][n] ----------------
__global__ void k_w1_psum(const float* __restrict__ w1, float* __restrict__ psum) {
    int c = blockIdx.x, t = threadIdx.x;
    const float* p = w1 + (size_t)c * 64 * T_ + t;
    float s = 0.f;
    #pragma unroll 8
    for (int r = 0; r < 64; ++r) s += p[(size_t)r * T_];
    psum[c * T_ + t] = s;
}

__global__ void k_w1_scan(const float* __restrict__ psum, float* __restrict__ offs) {
    int t = threadIdx.x;
    float run = 0.f;
    for (int c = 0; c < 128; ++c) {
        offs[c * T_ + t] = run;
        run += psum[c * T_ + t];
    }
}

// w1ct row t (16KB): per 64-n chunk c: byte = (t*16384) + c*128 + ((nl*2) ^ ((t&7)<<4))
__global__ void k_w1_prefix(const float* __restrict__ w1, const float* __restrict__ offs,
                            unsigned short* __restrict__ w1ct) {
    int c = blockIdx.x, t = threadIdx.x;     // c: n-chunk 0..127
    float run = offs[c * T_ + t];
    const float* p = w1 + (size_t)c * 64 * T_ + t;
    unsigned int wb[32];
    #pragma unroll
    for (int q = 0; q < 32; ++q) {
        run += p[(size_t)(2 * q) * T_];
        unsigned int lo = f2bf(run);
        run += p[(size_t)(2 * q + 1) * T_];
        wb[q] = lo | ((unsigned int)f2bf(run) << 16);
    }
    char* row = (char*)w1ct + ((size_t)t * N_ + c * 64) * 2;
    int key = (t & 7) << 4;
    #pragma unroll
    for (int pc = 0; pc < 8; ++pc) {
        int4 v = { (int)wb[4*pc], (int)wb[4*pc+1], (int)wb[4*pc+2], (int)wb[4*pc+3] };
        *(int4*)(row + ((pc * 16) ^ key)) = v;
    }
}

// ---------------- tok_w2 transpose -> swizzled bf16 w2t[n][t] (512B rows) ----------------
__global__ void k_w2t_pack(const float* __restrict__ w2, unsigned short* __restrict__ w2t) {
    __shared__ float ld[64 * 68];
    int nt = blockIdx.x, tt = blockIdx.y;   // 128 n-tiles x 4 t-tiles (64x64)
    int n0 = nt * 64, t0 = tt * 64;
    int tid = threadIdx.x;
    #pragma unroll
    for (int rnd = 0; rnd < 4; ++rnd) {
        int idx = tid + rnd * 256;
        int tr = idx >> 4, nc = idx & 15;
        float4 v = *(const float4*)(w2 + (size_t)(t0 + tr) * N_ + n0 + nc * 4);
        *(float4*)&ld[tr * 68 + nc * 4] = v;
    }
    __syncthreads();
    int n = tid >> 2, q = tid & 3;
    int key = (n & 7) << 4;
    unsigned int wb[8];
    #pragma unroll
    for (int j = 0; j < 8; ++j) {
        float a = ld[(q * 16 + 2 * j) * 68 + n];
        float b = ld[(q * 16 + 2 * j + 1) * 68 + n];
        wb[j] = (unsigned int)f2bf(a) | ((unsigned int)f2bf(b) << 16);
    }
    char* row = (char*)w2t + (size_t)(n0 + n) * 512 + t0 * 2;
    int4 v0 = { (int)wb[0], (int)wb[1], (int)wb[2], (int)wb[3] };
    int4 v1 = { (int)wb[4], (int)wb[5], (int)wb[6], (int)wb[7] };
    *(int4*)(row + ((q * 32) ^ key)) = v0;
    *(int4*)(row + ((q * 32 + 16) ^ key)) = v1;
}

// ---------------- ch-weight prepack (feeds k_chmlp2) ----------------
__global__ void k_pack1(const float* __restrict__ w1, unsigned short* __restrict__ w1p) {
    int e = blockIdx.x * 256 + threadIdx.x;
    int c = e >> 13, t = e & 8191;
    int n = t >> 7, j = t & 127;
    int k = j ^ ((n & 7) << 3);
    int hid = c * 64 + n;
    w1p[e] = f2bf(w1[(size_t)k * C_ + hid]);
}

__global__ void k_pack2(const float* __restrict__ w2, unsigned short* __restrict__ w2p) {
    int e = blockIdx.x * 256 + threadIdx.x;
    int c = e >> 13, t = e & 8191;
    int n = t >> 6, j = t & 63;
    int k = j ^ ((n & 7) << 3);
    w2p[e] = f2bf(w2[(size_t)(c * 64 + k) * H_ + n]);
}

// ---------------- LN1 + transpose -> y1t[b][h][n] bf16, rows swizzled per 64-n chunk ----------------
__global__ void k_lnT(const float* __restrict__ x, const float* __restrict__ g,
                      const float* __restrict__ bb, unsigned short* __restrict__ y1t) {
    __shared__ float ln[64 * 129];
    int tid = threadIdx.x;
    int wave = tid >> 6, lane = tid & 63;
    size_t base = (size_t)blockIdx.x * 64;
    float2 gg = *(const float2*)(g + lane * 2);
    float2 bv = *(const float2*)(bb + lane * 2);
    for (int rr = 0; rr < 16; ++rr) {
        int r = wave * 16 + rr;
        float2 v = *(const float2*)(x + (base + r) * H_ + lane * 2);
        float s = v.x + v.y, ss = v.x * v.x + v.y * v.y;
        #pragma unroll
        for (int off = 32; off; off >>= 1) { s += __shfl_xor(s, off); ss += __shfl_xor(ss, off); }
        float mean = s * (1.f / 128.f);
        float rstd = rsqrtf(ss * (1.f / 128.f) - mean * mean + 1e-5f);
        ln[r * 129 + lane * 2]     = (v.x - mean) * rstd * gg.x + bv.x;
        ln[r * 129 + lane * 2 + 1] = (v.y - mean) * rstd * gg.y + bv.y;
    }
    __syncthreads();
    int h = tid >> 1, half = tid & 1;
    unsigned int wb[16];
    #pragma unroll
    for (int q = 0; q < 16; ++q) {
        float a = ln[(half * 32 + 2 * q) * 129 + h];
        float b = ln[(half * 32 + 2 * q + 1) * 129 + h];
        wb[q] = (unsigned int)f2bf(a) | ((unsigned int)f2bf(b) << 16);
    }
    int b_ = (int)(base >> 13);
    int n0 = (int)(base & (N_ - 1));
    char* row = (char*)y1t + (((size_t)b_ * H_ + h) * N_ + n0) * 2;
    int key = (h & 7) << 4;
    #pragma unroll
    for (int pc = 0; pc < 4; ++pc) {
        int4 v = { (int)wb[4*pc], (int)wb[4*pc+1], (int)wb[4*pc+2], (int)wb[4*pc+3] };
        *(int4*)(row + ((half * 64 + pc * 16) ^ key)) = v;
    }
}

// ---------------- token GEMM1: bf16 MFMA, split-K 16 -> f32 partials ----------------
#define T1_YS 0        // 16KB: ys[h=128][128B swz]
#define T1_WS 16384    // 32KB: ws[t=256][128B swz]

__global__ __launch_bounds__(512, 1)
void k_tok1(const unsigned short* __restrict__ y1t, const unsigned short* __restrict__ w1ct,
            float* __restrict__ P) {
    __shared__ __align__(16) char sm[49152];
    int kk = blockIdx.x, b = blockIdx.y;
    int tid = threadIdx.x;
    int w = tid >> 6, lane = tid & 63;
    int lr = lane & 15, lk = lane >> 4;
    int mg = w >> 2, ng = w & 3;           // wave tile: 64h x 64t
    const char* yb = (const char*)y1t + (size_t)b * H_ * N_ * 2;
    const char* wbg = (const char*)w1ct;
    int kbase = kk * 512;

    f32x4 acc[4][4];
    #pragma unroll
    for (int i = 0; i < 4; ++i)
        #pragma unroll
        for (int j = 0; j < 4; ++j) acc[i][j] = (f32x4){0.f, 0.f, 0.f, 0.f};

    for (int s = 0; s < 8; ++s) {
        int n0 = kbase + s * 64;
        __syncthreads();
        #pragma unroll
        for (int rnd = 0; rnd < 2; ++rnd) {
            int idx = tid + rnd * 512;
            int hr = idx >> 3, p = idx & 7;
            gl2lds16(yb + ((size_t)hr * N_ + n0) * 2 + p * 16, sm + T1_YS + idx * 16);
        }
        #pragma unroll
        for (int rnd = 0; rnd < 4; ++rnd) {
            int idx = tid + rnd * 512;
            int tr = idx >> 3, p = idx & 7;
            gl2lds16(wbg + ((size_t)tr * N_ + n0) * 2 + p * 16, sm + T1_WS + idx * 16);
        }
        __syncthreads();
        #pragma unroll
        for (int ks = 0; ks < 2; ++ks) {
            bf16x8 af[4], bfr[4];
            #pragma unroll
            for (int i = 0; i < 4; ++i) {
                int h = mg * 64 + i * 16 + lr;
                af[i] = *(const bf16x8*)(sm + T1_YS + h * 128 + ((ks * 64 + lk * 16) ^ ((h & 7) << 4)));
            }
            #pragma unroll
            for (int j = 0; j < 4; ++j) {
                int t = ng * 64 + j * 16 + lr;
                bfr[j] = *(const bf16x8*)(sm + T1_WS + t * 128 + ((ks * 64 + lk * 16) ^ ((t & 7) << 4)));
            }
            #pragma unroll
            for (int i = 0; i < 4; ++i)
                #pragma unroll
                for (int j = 0; j < 4; ++j)
                    acc[i][j] = __builtin_amdgcn_mfma_f32_16x16x32_bf16(af[i], bfr[j], acc[i][j], 0, 0, 0);
        }
    }

    float* Pb = P + ((size_t)(b * 16 + kk)) * (H_ * T_);
    #pragma unroll
    for (int i = 0; i < 4; ++i)
        #pragma unroll
        for (int j = 0; j < 4; ++j) {
            int t = ng * 64 + j * 16 + lr;
            #pragma unroll
            for (int r = 0; r < 4; ++r) {
                int h = mg * 64 + i * 16 + lk * 4 + r;
                Pb[h * T_ + t] = acc[i][j][r];
            }
        }
}

// ---------------- combine partials + bias + gelu -> g1b bf16 [b][h][t] swizzled ----------------
__global__ void k_tok1_fin(const float* __restrict__ P, const float* __restrict__ b1,
                           unsigned short* __restrict__ g1b) {
    int fid = blockIdx.x * 256 + threadIdx.x;
    int base = fid * 4;
    int b = base >> 15, rem = base & 32767;
    int h = rem >> 8, t = rem & 255;
    const float* Pb = P + (size_t)b * 16 * 32768 + rem;
    float4 a = *(const float4*)Pb;
    #pragma unroll
    for (int kk = 1; kk < 16; ++kk) {
        float4 p = *(const float4*)(Pb + (size_t)kk * 32768);
        a.x += p.x; a.y += p.y; a.z += p.z; a.w += p.w;
    }
    float4 bb = *(const float4*)(b1 + t);
    unsigned int lo = (unsigned int)f2bf(gelu_f(a.x + bb.x)) | ((unsigned int)f2bf(gelu_f(a.y + bb.y)) << 16);
    unsigned int hi = (unsigned int)f2bf(gelu_f(a.z + bb.z)) | ((unsigned int)f2bf(gelu_f(a.w + bb.w)) << 16);
    char* row = (char*)g1b + (size_t)(b * H_ + h) * 512;
    uint2 v = { lo, hi };
    *(uint2*)(row + ((t * 2) ^ ((h & 7) << 4))) = v;
}

// ---------------- token GEMM2 + tok_b2 + LN2 + bf16 swizzle-pack -> y2p tiles ----------------
#define T2_AS 0        // 64KB: w2t tile (rows tok, 512B swz)
#define T2_BS 65536    // 64KB: g1b[b]  (rows h,   512B swz)

__global__ __launch_bounds__(512, 1)
void k_tok2ln(const unsigned short* __restrict__ g1b, const unsigned short* __restrict__ w2t,
              const float* __restrict__ tb2, const float* __restrict__ lg,
              const float* __restrict__ lb, unsigned short* __restrict__ y2p) {
    __shared__ __align__(16) char sm[131072];
    int nt = blockIdx.x, b = blockIdx.y;
    int tid = threadIdx.x;
    int w = tid >> 6, lane = tid & 63;
    int lr = lane & 15, lk = lane >> 4;
    const char* ab = (const char*)w2t + (size_t)(nt * 128) * 512;
    const char* gb = (const char*)g1b + (size_t)b * H_ * 512;

    #pragma unroll
    for (int rnd = 0; rnd < 8; ++rnd) {
        int idx = tid + rnd * 512;
        gl2lds16(ab + (size_t)idx * 16, sm + T2_AS + idx * 16);
        gl2lds16(gb + (size_t)idx * 16, sm + T2_BS + idx * 16);
    }
    __syncthreads();

    f32x4 acc[8];
    #pragma unroll
    for (int g = 0; g < 8; ++g) acc[g] = (f32x4){0.f, 0.f, 0.f, 0.f};
    int arow = w * 16 + lr;
    const char* aptr = sm + T2_AS + arow * 512;
    int akey = (arow & 7) << 4;
    #pragma unroll
    for (int ks = 0; ks < 8; ++ks) {
        bf16x8 af = *(const bf16x8*)(aptr + ((ks * 64 + lk * 16) ^ akey));
        #pragma unroll
        for (int g = 0; g < 8; ++g) {
            int hrow = g * 16 + lr;
            bf16x8 bf_ = *(const bf16x8*)(sm + T2_BS + hrow * 512 + ((ks * 64 + lk * 16) ^ ((hrow & 7) << 4)));
            acc[g] = __builtin_amdgcn_mfma_f32_16x16x32_bf16(af, bf_, acc[g], 0, 0, 0);
        }
    }

    float gam[8], bet[8];
    #pragma unroll
    for (int g = 0; g < 8; ++g) { gam[g] = lg[g * 16 + lr]; bet[g] = lb[g * 16 + lr]; }
    __syncthreads();   // all waves done reading sm; reuse rows [0,32KB) for y2p tile image

    #pragma unroll
    for (int r = 0; r < 4; ++r) {
        int row = w * 16 + lk * 4 + r;
        float bias2 = tb2[nt * 128 + row];
        float vals[8];
        float s = 0.f, ss = 0.f;
        #pragma unroll
        for (int g = 0; g < 8; ++g) {
            float v = acc[g][r] + bias2;
            vals[g] = v; s += v; ss += v * v;
        }
        #pragma unroll
        for (int off = 8; off; off >>= 1) { s += __shfl_xor(s, off); ss += __shfl_xor(ss, off); }
        float mean = s * (1.f / 128.f);
        float rstd = rsqrtf(ss * (1.f / 128.f) - mean * mean + 1e-5f);
        int key = (row & 7) << 4;
        char* orow = sm + row * 256;
        #pragma unroll
        for (int g = 0; g < 8; ++g) {
            float v = (vals[g] - mean) * rstd * gam[g] + bet[g];
            *(unsigned short*)(orow + (((g * 16 + lr) * 2) ^ key)) = f2bf(v);
        }
    }
    __syncthreads();
    char* dst = (char*)y2p + (size_t)(b * 64 + nt) * 32768;
    #pragma unroll
    for (int rnd = 0; rnd < 4; ++rnd) {
        int idx = tid + rnd * 512;
        *(int4*)(dst + idx * 16) = *(const int4*)(sm + idx * 16);
    }
}

// ---------------- fused channel MLP via bf16 MFMA ----------------
// GEMM1 uses SWAPPED mfma operands so each lane's 4 acc entries are 4
// consecutive hid for one tok -> gelu+pack -> single ds_write_b64 into hs.
#define LDS_YS 0
#define LDS_HS 32768
#define LDS_W1 49152
#define LDS_W2 65536

__global__ __launch_bounds__(512, 4)
void k_chmlp2(const unsigned short* __restrict__ y2p, const unsigned short* __restrict__ w1p,
              const unsigned short* __restrict__ w2p, const float* __restrict__ b1g,
              const float* __restrict__ b2g, float* __restrict__ out) {
    __shared__ __align__(16) char sm[81920];
    int tid = threadIdx.x;
    int w = tid >> 6, lane = tid & 63;
    int tile = blockIdx.x;
    const char* ybase = (const char*)y2p + (size_t)tile * 32768;
    const char* w1b = (const char*)w1p;
    const char* w2b = (const char*)w2p;

    #pragma unroll
    for (int j = 0; j < 4; ++j)
        gl2lds16(ybase + w * 4096 + j * 1024 + lane * 16, sm + LDS_YS + w * 4096 + j * 1024);
    #pragma unroll
    for (int j = 0; j < 2; ++j) {
        gl2lds16(w1b + w * 2048 + j * 1024 + lane * 16, sm + LDS_W1 + w * 2048 + j * 1024);
        gl2lds16(w2b + w * 2048 + j * 1024 + lane * 16, sm + LDS_W2 + w * 2048 + j * 1024);
    }
    __syncthreads();

    int mg = w >> 1, ng = w & 1;
    int lr = lane & 15, lk = lane >> 4;
    int key = (lr & 7) << 4;

    f32x4 oacc[2][4];
    #pragma unroll
    for (int m = 0; m < 2; ++m)
        #pragma unroll
        for (int n = 0; n < 4; ++n) oacc[m][n] = (f32x4){0.f, 0.f, 0.f, 0.f};

    for (int c = 0; c < 8; ++c) {
        // ---- GEMM1 (swapped): hacc[m][n] rows = hid, cols = tok
        f32x4 hacc[2][2];
        #pragma unroll
        for (int n = 0; n < 2; ++n) {
            float4 bv4 = *(const float4*)(b1g + c * 64 + (2 * ng + n) * 16 + lk * 4);
            f32x4 iv = { bv4.x, bv4.y, bv4.z, bv4.w };
            hacc[0][n] = iv;
            hacc[1][n] = iv;
        }
        #pragma unroll
        for (int kc = 0; kc < 4; ++kc) {
            int ko = kc * 64 + lk * 16;
            bf16x8 a0 = *(const bf16x8*)(sm + LDS_YS + ((2 * mg) * 16 + lr) * 256 + (ko ^ key));
            bf16x8 a1 = *(const bf16x8*)(sm + LDS_YS + ((2 * mg + 1) * 16 + lr) * 256 + (ko ^ key));
            bf16x8 b0 = *(const bf16x8*)(sm + LDS_W1 + ((2 * ng) * 16 + lr) * 256 + (ko ^ key));
            bf16x8 b1 = *(const bf16x8*)(sm + LDS_W1 + ((2 * ng + 1) * 16 + lr) * 256 + (ko ^ key));
            hacc[0][0] = __builtin_amdgcn_mfma_f32_16x16x32_bf16(b0, a0, hacc[0][0], 0, 0, 0);
            hacc[0][1] = __builtin_amdgcn_mfma_f32_16x16x32_bf16(b1, a0, hacc[0][1], 0, 0, 0);
            hacc[1][0] = __builtin_amdgcn_mfma_f32_16x16x32_bf16(b0, a1, hacc[1][0], 0, 0, 0);
            hacc[1][1] = __builtin_amdgcn_mfma_f32_16x16x32_bf16(b1, a1, hacc[1][1], 0, 0, 0);
        }
        // gelu -> hs[tok][hid] rows 128B, swizzled; 4 consecutive hid per lane -> b64 write
        #pragma unroll
        for (int m = 0; m < 2; ++m)
            #pragma unroll
            for (int n = 0; n < 2; ++n) {
                int tok = (2 * mg + m) * 16 + lr;
                int hid0 = (2 * ng + n) * 16 + lk * 4;
                bf16x4 pv;
                pv[0] = (__bf16)gelu_f(hacc[m][n][0]);
                pv[1] = (__bf16)gelu_f(hacc[m][n][1]);
                pv[2] = (__bf16)gelu_f(hacc[m][n][2]);
                pv[3] = (__bf16)gelu_f(hacc[m][n][3]);
                *(bf16x4*)(sm + LDS_HS + tok * 128 + ((hid0 * 2) ^ ((tok & 7) << 4))) = pv;
            }
        __syncthreads();
        if (c < 7) {
            #pragma unroll
            for (int j = 0; j < 2; ++j)
                gl2lds16(w1b + (c + 1) * 16384 + w * 2048 + j * 1024 + lane * 16,
                         sm + LDS_W1 + w * 2048 + j * 1024);
        }
        // ---- GEMM2: out[2m][4n] += hs(tok,64hid) @ w2c(128ch,64hid^T), K=64
        #pragma unroll
        for (int kc = 0; kc < 2; ++kc) {
            int ko = kc * 64 + lk * 16;
            bf16x8 a0 = *(const bf16x8*)(sm + LDS_HS + ((2 * mg) * 16 + lr) * 128 + (ko ^ key));
            bf16x8 a1 = *(const bf16x8*)(sm + LDS_HS + ((2 * mg + 1) * 16 + lr) * 128 + (ko ^ key));
            #pragma unroll
            for (int n = 0; n < 4; ++n) {
                bf16x8 bb = *(const bf16x8*)(sm + LDS_W2 + ((ng * 4 + n) * 16 + lr) * 128 + (ko ^ key));
                oacc[0][n] = __builtin_amdgcn_mfma_f32_16x16x32_bf16(a0, bb, oacc[0][n], 0, 0, 0);
                oacc[1][n] = __builtin_amdgcn_mfma_f32_16x16x32_bf16(a1, bb, oacc[1][n], 0, 0, 0);
            }
        }
        __syncthreads();
        if (c < 7) {
            #pragma unroll
            for (int j = 0; j < 2; ++j)
                gl2lds16(w2b + (c + 1) * 16384 + w * 2048 + j * 1024 + lane * 16,
                         sm + LDS_W2 + w * 2048 + j * 1024);
        }
    }

    #pragma unroll
    for (int n = 0; n < 4; ++n) {
        int ch = (ng * 4 + n) * 16 + lr;
        float bv = b2g[ch];
        #pragma unroll
        for (int m = 0; m < 2; ++m)
            #pragma unroll
            for (int r = 0; r < 4; ++r) {
                size_t row = (size_t)tile * 128 + (2 * mg + m) * 16 + lk * 4 + r;
                out[row * H_ + ch] = oacc[m][n][r] + bv;
            }
    }
}

extern "C" void kernel_launch(void* const* d_in, const int* in_sizes, int n_in,
                              void* d_out, int out_size, void* d_ws, size_t ws_size,
                              hipStream_t stream) {
    const float* x      = (const float*)d_in[0];
    const float* ln1_g  = (const float*)d_in[1];
    const float* ln1_b  = (const float*)d_in[2];
    const float* ln2_g  = (const float*)d_in[3];
    const float* ln2_b  = (const float*)d_in[4];
    const float* tok_w1 = (const float*)d_in[5];
    const float* tok_b1 = (const float*)d_in[6];
    const float* tok_w2 = (const float*)d_in[7];
    const float* tok_b2 = (const float*)d_in[8];
    const float* ch_w1  = (const float*)d_in[9];
    const float* ch_b1  = (const float*)d_in[10];
    const float* ch_w2  = (const float*)d_in[11];
    const float* ch_b2  = (const float*)d_in[12];
    float* out = (float*)d_out;
    float* ws  = (float*)d_ws;

    float* psum = ws;                                         //    32,768 f
    float* offs = ws + 32768;                                 //    32,768 f
    unsigned short* w1ct = (unsigned short*)(ws + 65536);     // 2M bf16 (4 MB)
    unsigned short* w2t  = (unsigned short*)(ws + 1114112);   // 2M bf16 (4 MB)
    unsigned short* w1p  = (unsigned short*)(ws + 2162688);   // 64K bf16
    unsigned short* w2p  = (unsigned short*)(ws + 2195456);   // 64K bf16
    unsigned short* y1t  = (unsigned short*)(ws + 2228224);   // 16M bf16 (32 MB)
    unsigned short* g1b  = (unsigned short*)(ws + 10616832);  // 512K bf16 (1 MB)
    float* P             = ws + 10878976;                     // 8M f32 (32 MB)
    unsigned short* y2p  = (unsigned short*)(ws + 10878976);  // overlays P (dead after fin)
    // total: 19,267,584 f32 = 77.1 MB

    k_w1_psum<<<dim3(128), dim3(256), 0, stream>>>(tok_w1, psum);
    k_w1_scan<<<dim3(1), dim3(256), 0, stream>>>(psum, offs);
    k_w1_prefix<<<dim3(128), dim3(256), 0, stream>>>(tok_w1, offs, w1ct);
    k_w2t_pack<<<dim3(128, 4), dim3(256), 0, stream>>>(tok_w2, w2t);
    k_pack1<<<dim3(256), dim3(256), 0, stream>>>(ch_w1, w1p);
    k_pack2<<<dim3(256), dim3(256), 0, stream>>>(ch_w2, w2p);
    k_lnT<<<dim3((B_ * N_) / 64), dim3(256), 0, stream>>>(x, ln1_g, ln1_b, y1t);
    k_tok1<<<dim3(16, 16), dim3(512), 0, stream>>>(y1t, w1ct, P);
    k_tok1_fin<<<dim3(512), dim3(256), 0, stream>>>(P, tok_b1, g1b);
    k_tok2ln<<<dim3(64, 16), dim3(512), 0, stream>>>(g1b, w2t, tok_b2, ln2_g, ln2_b, y2p);
    k_chmlp2<<<dim3((B_ * N_) / 128), dim3(512), 0, stream>>>(y2p, w1p, w2p, ch_b1, ch_b2, out);
}

// Round 5
// 140.604 us; speedup vs baseline: 5.7798x; 1.1282x over previous
//
#include <hip/hip_runtime.h>
#include <math.h>

#define B_ 16
#define N_ 8192
#define H_ 128
#define T_ 256   // TOK_MLP
#define C_ 512   // CH_MLP

typedef __bf16 bf16x8 __attribute__((ext_vector_type(8)));
typedef __bf16 bf16x4 __attribute__((ext_vector_type(4)));
typedef float f32x4 __attribute__((ext_vector_type(4)));

// tanh-form gelu: x * sigmoid(1.5957691(x + 0.044715 x^3)).
__device__ __forceinline__ float gelu_f(float x) {
    float p = fmaf(0.044715f * x * x, x, x);
    float e = __expf(-1.5957691216057308f * p);
    return x * __builtin_amdgcn_rcpf(1.f + e);
}

__device__ __forceinline__ unsigned short f2bf(float x) {
    unsigned int u = __float_as_uint(x);
    u = (u + 0x7FFFu + ((u >> 16) & 1u)) >> 16;
    return (unsigned short)u;
}

__device__ __forceinline__ void gl2lds16(const void* g, void* l) {
    __builtin_amdgcn_global_load_lds(
        (const __attribute__((address_space(1))) void*)g,
        (__attribute__((address_space(3))) void*)l,
        16, 0, 0);
}

// ---------------- tok_w1 prefix cumsum -> transposed swizzled bf16 w1ct[t][n] ----------------
__global__ void k_w1_psum(const float* __restrict__ w1, float* __restrict__ psum) {
    int c = blockIdx.x, t = threadIdx.x;
    const float* p = w1 + (size_t)c * 64 * T_ + t;
    float s = 0.f;
    #pragma unroll 8
    for (int r = 0; r < 64; ++r) s += p[(size_t)r * T_];
    psum[c * T_ + t] = s;
}

__global__ void k_w1_scan(const float* __restrict__ psum, float* __restrict__ offs) {
    int t = threadIdx.x;
    float run = 0.f;
    for (int c = 0; c < 128; ++c) {
        offs[c * T_ + t] = run;
        run += psum[c * T_ + t];
    }
}

// w1ct row t (16KB): per 64-n chunk c: byte = (t*16384) + c*128 + ((nl*2) ^ ((t&7)<<4))
__global__ void k_w1_prefix(const float* __restrict__ w1, const float* __restrict__ offs,
                            unsigned short* __restrict__ w1ct) {
    int c = blockIdx.x, t = threadIdx.x;     // c: n-chunk 0..127
    float run = offs[c * T_ + t];
    const float* p = w1 + (size_t)c * 64 * T_ + t;
    unsigned int wb[32];
    #pragma unroll
    for (int q = 0; q < 32; ++q) {
        run += p[(size_t)(2 * q) * T_];
        unsigned int lo = f2bf(run);
        run += p[(size_t)(2 * q + 1) * T_];
        wb[q] = lo | ((unsigned int)f2bf(run) << 16);
    }
    char* row = (char*)w1ct + ((size_t)t * N_ + c * 64) * 2;
    int key = (t & 7) << 4;
    #pragma unroll
    for (int pc = 0; pc < 8; ++pc) {
        int4 v = { (int)wb[4*pc], (int)wb[4*pc+1], (int)wb[4*pc+2], (int)wb[4*pc+3] };
        *(int4*)(row + ((pc * 16) ^ key)) = v;
    }
}

// ---------------- tok_w2 transpose -> swizzled bf16 w2t[n][t] (512B rows) ----------------
__global__ void k_w2t_pack(const float* __restrict__ w2, unsigned short* __restrict__ w2t) {
    __shared__ float ld[64 * 68];
    int nt = blockIdx.x, tt = blockIdx.y;   // 128 n-tiles x 4 t-tiles (64x64)
    int n0 = nt * 64, t0 = tt * 64;
    int tid = threadIdx.x;
    #pragma unroll
    for (int rnd = 0; rnd < 4; ++rnd) {
        int idx = tid + rnd * 256;
        int tr = idx >> 4, nc = idx & 15;
        float4 v = *(const float4*)(w2 + (size_t)(t0 + tr) * N_ + n0 + nc * 4);
        *(float4*)&ld[tr * 68 + nc * 4] = v;
    }
    __syncthreads();
    int n = tid >> 2, q = tid & 3;
    int key = (n & 7) << 4;
    unsigned int wb[8];
    #pragma unroll
    for (int j = 0; j < 8; ++j) {
        float a = ld[(q * 16 + 2 * j) * 68 + n];
        float b = ld[(q * 16 + 2 * j + 1) * 68 + n];
        wb[j] = (unsigned int)f2bf(a) | ((unsigned int)f2bf(b) << 16);
    }
    char* row = (char*)w2t + (size_t)(n0 + n) * 512 + t0 * 2;
    int4 v0 = { (int)wb[0], (int)wb[1], (int)wb[2], (int)wb[3] };
    int4 v1 = { (int)wb[4], (int)wb[5], (int)wb[6], (int)wb[7] };
    *(int4*)(row + ((q * 32) ^ key)) = v0;
    *(int4*)(row + ((q * 32 + 16) ^ key)) = v1;
}

// ---------------- ch-weight prepack ----------------
__global__ void k_pack1(const float* __restrict__ w1, unsigned short* __restrict__ w1p) {
    int e = blockIdx.x * 256 + threadIdx.x;
    int c = e >> 13, t = e & 8191;
    int n = t >> 7, j = t & 127;
    int k = j ^ ((n & 7) << 3);
    int hid = c * 64 + n;
    w1p[e] = f2bf(w1[(size_t)k * C_ + hid]);
}

__global__ void k_pack2(const float* __restrict__ w2, unsigned short* __restrict__ w2p) {
    int e = blockIdx.x * 256 + threadIdx.x;
    int c = e >> 13, t = e & 8191;
    int n = t >> 6, j = t & 63;
    int k = j ^ ((n & 7) << 3);
    w2p[e] = f2bf(w2[(size_t)(c * 64 + k) * H_ + n]);
}

// ---------------- LN1 + transpose -> y1t[b][h][n] bf16, rows swizzled per 64-n chunk ----------------
__global__ void k_lnT(const float* __restrict__ x, const float* __restrict__ g,
                      const float* __restrict__ bb, unsigned short* __restrict__ y1t) {
    __shared__ float ln[64 * 129];
    int tid = threadIdx.x;
    int wave = tid >> 6, lane = tid & 63;
    size_t base = (size_t)blockIdx.x * 64;
    float2 gg = *(const float2*)(g + lane * 2);
    float2 bv = *(const float2*)(bb + lane * 2);
    for (int rr = 0; rr < 16; ++rr) {
        int r = wave * 16 + rr;
        float2 v = *(const float2*)(x + (base + r) * H_ + lane * 2);
        float s = v.x + v.y, ss = v.x * v.x + v.y * v.y;
        #pragma unroll
        for (int off = 32; off; off >>= 1) { s += __shfl_xor(s, off); ss += __shfl_xor(ss, off); }
        float mean = s * (1.f / 128.f);
        float rstd = rsqrtf(ss * (1.f / 128.f) - mean * mean + 1e-5f);
        ln[r * 129 + lane * 2]     = (v.x - mean) * rstd * gg.x + bv.x;
        ln[r * 129 + lane * 2 + 1] = (v.y - mean) * rstd * gg.y + bv.y;
    }
    __syncthreads();
    int h = tid >> 1, half = tid & 1;
    unsigned int wb[16];
    #pragma unroll
    for (int q = 0; q < 16; ++q) {
        float a = ln[(half * 32 + 2 * q) * 129 + h];
        float b = ln[(half * 32 + 2 * q + 1) * 129 + h];
        wb[q] = (unsigned int)f2bf(a) | ((unsigned int)f2bf(b) << 16);
    }
    int b_ = (int)(base >> 13);
    int n0 = (int)(base & (N_ - 1));
    char* row = (char*)y1t + (((size_t)b_ * H_ + h) * N_ + n0) * 2;
    int key = (h & 7) << 4;
    #pragma unroll
    for (int pc = 0; pc < 4; ++pc) {
        int4 v = { (int)wb[4*pc], (int)wb[4*pc+1], (int)wb[4*pc+2], (int)wb[4*pc+3] };
        *(int4*)(row + ((half * 64 + pc * 16) ^ key)) = v;
    }
}

// ---------------- token GEMM1: bf16 MFMA, split-K 16 -> f32 partials ----------------
#define T1_YS 0        // 16KB: ys[h=128][128B swz]
#define T1_WS 16384    // 32KB: ws[t=256][128B swz]

__global__ __launch_bounds__(512, 1)
void k_tok1(const unsigned short* __restrict__ y1t, const unsigned short* __restrict__ w1ct,
            float* __restrict__ P) {
    __shared__ __align__(16) char sm[49152];
    int kk = blockIdx.x, b = blockIdx.y;
    int tid = threadIdx.x;
    int w = tid >> 6, lane = tid & 63;
    int lr = lane & 15, lk = lane >> 4;
    int mg = w >> 2, ng = w & 3;           // wave tile: 64h x 64t
    const char* yb = (const char*)y1t + (size_t)b * H_ * N_ * 2;
    const char* wbg = (const char*)w1ct;
    int kbase = kk * 512;

    f32x4 acc[4][4];
    #pragma unroll
    for (int i = 0; i < 4; ++i)
        #pragma unroll
        for (int j = 0; j < 4; ++j) acc[i][j] = (f32x4){0.f, 0.f, 0.f, 0.f};

    for (int s = 0; s < 8; ++s) {
        int n0 = kbase + s * 64;
        __syncthreads();
        #pragma unroll
        for (int rnd = 0; rnd < 2; ++rnd) {
            int idx = tid + rnd * 512;
            int hr = idx >> 3, p = idx & 7;
            gl2lds16(yb + ((size_t)hr * N_ + n0) * 2 + p * 16, sm + T1_YS + idx * 16);
        }
        #pragma unroll
        for (int rnd = 0; rnd < 4; ++rnd) {
            int idx = tid + rnd * 512;
            int tr = idx >> 3, p = idx & 7;
            gl2lds16(wbg + ((size_t)tr * N_ + n0) * 2 + p * 16, sm + T1_WS + idx * 16);
        }
        __syncthreads();
        #pragma unroll
        for (int ks = 0; ks < 2; ++ks) {
            bf16x8 af[4], bfr[4];
            #pragma unroll
            for (int i = 0; i < 4; ++i) {
                int h = mg * 64 + i * 16 + lr;
                af[i] = *(const bf16x8*)(sm + T1_YS + h * 128 + ((ks * 64 + lk * 16) ^ ((h & 7) << 4)));
            }
            #pragma unroll
            for (int j = 0; j < 4; ++j) {
                int t = ng * 64 + j * 16 + lr;
                bfr[j] = *(const bf16x8*)(sm + T1_WS + t * 128 + ((ks * 64 + lk * 16) ^ ((t & 7) << 4)));
            }
            #pragma unroll
            for (int i = 0; i < 4; ++i)
                #pragma unroll
                for (int j = 0; j < 4; ++j)
                    acc[i][j] = __builtin_amdgcn_mfma_f32_16x16x32_bf16(af[i], bfr[j], acc[i][j], 0, 0, 0);
        }
    }

    float* Pb = P + ((size_t)(b * 16 + kk)) * (H_ * T_);
    #pragma unroll
    for (int i = 0; i < 4; ++i)
        #pragma unroll
        for (int j = 0; j < 4; ++j) {
            int t = ng * 64 + j * 16 + lr;
            #pragma unroll
            for (int r = 0; r < 4; ++r) {
                int h = mg * 64 + i * 16 + lk * 4 + r;
                Pb[h * T_ + t] = acc[i][j][r];
            }
        }
}

// ---------------- combine partials + bias + gelu -> g1b bf16 [b][h][t] swizzled ----------------
__global__ void k_tok1_fin(const float* __restrict__ P, const float* __restrict__ b1,
                           unsigned short* __restrict__ g1b) {
    int fid = blockIdx.x * 256 + threadIdx.x;
    int base = fid * 4;
    int b = base >> 15, rem = base & 32767;
    int h = rem >> 8, t = rem & 255;
    const float* Pb = P + (size_t)b * 16 * 32768 + rem;
    float4 a = *(const float4*)Pb;
    #pragma unroll
    for (int kk = 1; kk < 16; ++kk) {
        float4 p = *(const float4*)(Pb + (size_t)kk * 32768);
        a.x += p.x; a.y += p.y; a.z += p.z; a.w += p.w;
    }
    float4 bb = *(const float4*)(b1 + t);
    unsigned int lo = (unsigned int)f2bf(gelu_f(a.x + bb.x)) | ((unsigned int)f2bf(gelu_f(a.y + bb.y)) << 16);
    unsigned int hi = (unsigned int)f2bf(gelu_f(a.z + bb.z)) | ((unsigned int)f2bf(gelu_f(a.w + bb.w)) << 16);
    char* row = (char*)g1b + (size_t)(b * H_ + h) * 512;
    uint2 v = { lo, hi };
    *(uint2*)(row + ((t * 2) ^ ((h & 7) << 4))) = v;
}

// ---------------- FUSED: token GEMM2 + tok_b2 + LN2 + channel MLP ----------------
// Phase A: C[tok128][h128] = w2t_tile @ g1b[b]^T  (K=256 in 2 halves of 32KB staging)
//          + bias + LN2 -> bf16 tile in LDS [0,32K)
// Phase B: channel MLP on the tile (y-frags cached in regs; hs overlays dead ys)
// LDS: 64KB -> 2 blocks/CU.
#define F_AS 0        // phase A: w2t half (128 rows x 256B)   [0,32K)
#define F_BS 32768    // phase A: g1b half (128 rows x 256B)   [32K,64K)
#define F_YS 0        // ln2 tile (128 rows x 256B, swz)       [0,32K)
#define F_W1 32768    // ch_w1 chunk (64 rows x 256B, swz)     [32K,48K)
#define F_W2 49152    // ch_w2 chunk (128 rows x 128B, swz)    [48K,64K)
#define F_HS 0        // hs (128 rows x 144B, NO swz)          [0,18432) after y-frag cache

__global__ __launch_bounds__(512, 4)
void k_tok2mlp(const unsigned short* __restrict__ g1b, const unsigned short* __restrict__ w2t,
               const float* __restrict__ tb2, const float* __restrict__ lg,
               const float* __restrict__ lb, const unsigned short* __restrict__ w1p,
               const unsigned short* __restrict__ w2p, const float* __restrict__ b1g,
               const float* __restrict__ b2g, float* __restrict__ out) {
    __shared__ __align__(16) char sm[65536];
    int nt = blockIdx.x, b = blockIdx.y;
    int tid = threadIdx.x;
    int w = tid >> 6, lane = tid & 63;
    int lr = lane & 15, lk = lane >> 4;
    const char* ab = (const char*)w2t + (size_t)(nt * 128) * 512;
    const char* gb = (const char*)g1b + (size_t)b * H_ * 512;
    const char* w1b = (const char*)w1p;
    const char* w2b = (const char*)w2p;

    // ---- Phase A: tok GEMM2, K=256 in two 128-halves ----
    f32x4 acc[8];
    #pragma unroll
    for (int g = 0; g < 8; ++g) acc[g] = (f32x4){0.f, 0.f, 0.f, 0.f};

    for (int half = 0; half < 2; ++half) {
        __syncthreads();
        #pragma unroll
        for (int rnd = 0; rnd < 4; ++rnd) {
            int idx = tid + rnd * 512;                 // 0..2047
            int row = idx >> 4, p = idx & 15;          // 128 rows x 256B
            gl2lds16(ab + (size_t)row * 512 + half * 256 + p * 16, sm + F_AS + row * 256 + p * 16);
            gl2lds16(gb + (size_t)row * 512 + half * 256 + p * 16, sm + F_BS + row * 256 + p * 16);
        }
        __syncthreads();
        int arow = w * 16 + lr;
        const char* aptr = sm + F_AS + arow * 256;
        int akey = (arow & 7) << 4;
        #pragma unroll
        for (int ks = 0; ks < 4; ++ks) {
            bf16x8 af = *(const bf16x8*)(aptr + ((ks * 64 + lk * 16) ^ akey));
            #pragma unroll
            for (int g = 0; g < 8; ++g) {
                int hrow = g * 16 + lr;
                bf16x8 bf_ = *(const bf16x8*)(sm + F_BS + hrow * 256 + ((ks * 64 + lk * 16) ^ ((hrow & 7) << 4)));
                acc[g] = __builtin_amdgcn_mfma_f32_16x16x32_bf16(af, bf_, acc[g], 0, 0, 0);
            }
        }
    }

    float gam[8], bet[8];
    #pragma unroll
    for (int g = 0; g < 8; ++g) { gam[g] = lg[g * 16 + lr]; bet[g] = lb[g * 16 + lr]; }
    __syncthreads();   // all waves done with AS/BS

    // prefetch chunk-0 ch-weights into [32K,64K) (dead BS region), concurrent with LN2
    #pragma unroll
    for (int j = 0; j < 2; ++j) {
        gl2lds16(w1b + w * 2048 + j * 1024 + lane * 16, sm + F_W1 + w * 2048 + j * 1024);
        gl2lds16(w2b + w * 2048 + j * 1024 + lane * 16, sm + F_W2 + w * 2048 + j * 1024);
    }

    // LN2 -> ys tile [0,32K): rows tok 256B, byte (h*2)^((tok&7)<<4)
    #pragma unroll
    for (int r = 0; r < 4; ++r) {
        int row = w * 16 + lk * 4 + r;
        float bias2 = tb2[nt * 128 + row];
        float vals[8];
        float s = 0.f, ss = 0.f;
        #pragma unroll
        for (int g = 0; g < 8; ++g) {
            float v = acc[g][r] + bias2;
            vals[g] = v; s += v; ss += v * v;
        }
        #pragma unroll
        for (int off = 8; off; off >>= 1) { s += __shfl_xor(s, off); ss += __shfl_xor(ss, off); }
        float mean = s * (1.f / 128.f);
        float rstd = rsqrtf(ss * (1.f / 128.f) - mean * mean + 1e-5f);
        int key = (row & 7) << 4;
        char* orow = sm + F_YS + row * 256;
        #pragma unroll
        for (int g = 0; g < 8; ++g) {
            float v = (vals[g] - mean) * rstd * gam[g] + bet[g];
            *(unsigned short*)(orow + (((g * 16 + lr) * 2) ^ key)) = f2bf(v);
        }
    }
    __syncthreads();   // ys complete everywhere; chunk-0 weights staged (vmcnt drained)

    // ---- Phase B: channel MLP ----
    int mg = w >> 1, ng = w & 1;
    int key = (lr & 7) << 4;

    // cache y fragments (invariant across all 8 chunks): 2 m-rows x 4 kc
    bf16x8 yfrag[2][4];
    #pragma unroll
    for (int m = 0; m < 2; ++m) {
        int yrow = (2 * mg + m) * 16 + lr;
        #pragma unroll
        for (int kc = 0; kc < 4; ++kc)
            yfrag[m][kc] = *(const bf16x8*)(sm + F_YS + yrow * 256 + ((kc * 64 + lk * 16) ^ key));
    }
    __syncthreads();   // ys fully consumed -> hs may overlay [0,18432)

    f32x4 oacc[2][4];
    #pragma unroll
    for (int m = 0; m < 2; ++m)
        #pragma unroll
        for (int n = 0; n < 4; ++n) oacc[m][n] = (f32x4){0.f, 0.f, 0.f, 0.f};

    for (int c = 0; c < 8; ++c) {
        // GEMM1 (swapped): hacc rows = hid (lane-consecutive), cols = tok
        f32x4 hacc[2][2];
        #pragma unroll
        for (int n = 0; n < 2; ++n) {
            float4 bv4 = *(const float4*)(b1g + c * 64 + (2 * ng + n) * 16 + lk * 4);
            f32x4 iv = { bv4.x, bv4.y, bv4.z, bv4.w };
            hacc[0][n] = iv;
            hacc[1][n] = iv;
        }
        #pragma unroll
        for (int kc = 0; kc < 4; ++kc) {
            int ko = kc * 64 + lk * 16;
            bf16x8 b0 = *(const bf16x8*)(sm + F_W1 + ((2 * ng) * 16 + lr) * 256 + (ko ^ key));
            bf16x8 b1 = *(const bf16x8*)(sm + F_W1 + ((2 * ng + 1) * 16 + lr) * 256 + (ko ^ key));
            hacc[0][0] = __builtin_amdgcn_mfma_f32_16x16x32_bf16(b0, yfrag[0][kc], hacc[0][0], 0, 0, 0);
            hacc[0][1] = __builtin_amdgcn_mfma_f32_16x16x32_bf16(b1, yfrag[0][kc], hacc[0][1], 0, 0, 0);
            hacc[1][0] = __builtin_amdgcn_mfma_f32_16x16x32_bf16(b0, yfrag[1][kc], hacc[1][0], 0, 0, 0);
            hacc[1][1] = __builtin_amdgcn_mfma_f32_16x16x32_bf16(b1, yfrag[1][kc], hacc[1][1], 0, 0, 0);
        }
        // gelu -> hs: rows 144B, no swizzle; b64 write is 2-way (free)
        #pragma unroll
        for (int m = 0; m < 2; ++m)
            #pragma unroll
            for (int n = 0; n < 2; ++n) {
                int tok = (2 * mg + m) * 16 + lr;
                int hid0 = (2 * ng + n) * 16 + lk * 4;
                bf16x4 pv;
                pv[0] = (__bf16)gelu_f(hacc[m][n][0]);
                pv[1] = (__bf16)gelu_f(hacc[m][n][1]);
                pv[2] = (__bf16)gelu_f(hacc[m][n][2]);
                pv[3] = (__bf16)gelu_f(hacc[m][n][3]);
                *(bf16x4*)(sm + F_HS + tok * 144 + hid0 * 2) = pv;
            }
        __syncthreads();
        if (c < 7) {
            #pragma unroll
            for (int j = 0; j < 2; ++j)
                gl2lds16(w1b + (c + 1) * 16384 + w * 2048 + j * 1024 + lane * 16,
                         sm + F_W1 + w * 2048 + j * 1024);
        }
        // GEMM2: out += hs(tok,64hid) @ w2c(128ch,64hid^T)
        #pragma unroll
        for (int kc = 0; kc < 2; ++kc) {
            int ko = kc * 64 + lk * 16;
            bf16x8 a0 = *(const bf16x8*)(sm + F_HS + ((2 * mg) * 16 + lr) * 144 + ko);
            bf16x8 a1 = *(const bf16x8*)(sm + F_HS + ((2 * mg + 1) * 16 + lr) * 144 + ko);
            #pragma unroll
            for (int n = 0; n < 4; ++n) {
                bf16x8 bb = *(const bf16x8*)(sm + F_W2 + ((ng * 4 + n) * 16 + lr) * 128 + (ko ^ key));
                oacc[0][n] = __builtin_amdgcn_mfma_f32_16x16x32_bf16(a0, bb, oacc[0][n], 0, 0, 0);
                oacc[1][n] = __builtin_amdgcn_mfma_f32_16x16x32_bf16(a1, bb, oacc[1][n], 0, 0, 0);
            }
        }
        __syncthreads();
        if (c < 7) {
            #pragma unroll
            for (int j = 0; j < 2; ++j)
                gl2lds16(w2b + (c + 1) * 16384 + w * 2048 + j * 1024 + lane * 16,
                         sm + F_W2 + w * 2048 + j * 1024);
        }
    }

    // epilogue: + ch_b2, f32 store
    size_t rbase = (size_t)(b * 64 + nt) * 128;
    #pragma unroll
    for (int n = 0; n < 4; ++n) {
        int ch = (ng * 4 + n) * 16 + lr;
        float bv = b2g[ch];
        #pragma unroll
        for (int m = 0; m < 2; ++m)
            #pragma unroll
            for (int r = 0; r < 4; ++r) {
                size_t row = rbase + (2 * mg + m) * 16 + lk * 4 + r;
                out[row * H_ + ch] = oacc[m][n][r] + bv;
            }
    }
}

extern "C" void kernel_launch(void* const* d_in, const int* in_sizes, int n_in,
                              void* d_out, int out_size, void* d_ws, size_t ws_size,
                              hipStream_t stream) {
    const float* x      = (const float*)d_in[0];
    const float* ln1_g  = (const float*)d_in[1];
    const float* ln1_b  = (const float*)d_in[2];
    const float* ln2_g  = (const float*)d_in[3];
    const float* ln2_b  = (const float*)d_in[4];
    const float* tok_w1 = (const float*)d_in[5];
    const float* tok_b1 = (const float*)d_in[6];
    const float* tok_w2 = (const float*)d_in[7];
    const float* tok_b2 = (const float*)d_in[8];
    const float* ch_w1  = (const float*)d_in[9];
    const float* ch_b1  = (const float*)d_in[10];
    const float* ch_w2  = (const float*)d_in[11];
    const float* ch_b2  = (const float*)d_in[12];
    float* out = (float*)d_out;
    float* ws  = (float*)d_ws;

    float* psum = ws;                                         //    32,768 f
    float* offs = ws + 32768;                                 //    32,768 f
    unsigned short* w1ct = (unsigned short*)(ws + 65536);     // 2M bf16 (4 MB)
    unsigned short* w2t  = (unsigned short*)(ws + 1114112);   // 2M bf16 (4 MB)
    unsigned short* w1p  = (unsigned short*)(ws + 2162688);   // 64K bf16
    unsigned short* w2p  = (unsigned short*)(ws + 2195456);   // 64K bf16
    unsigned short* y1t  = (unsigned short*)(ws + 2228224);   // 16M bf16 (32 MB)
    unsigned short* g1b  = (unsigned short*)(ws + 10616832);  // 512K bf16 (1 MB)
    float* P             = ws + 10878976;                     // 8M f32 (32 MB)
    // total: 19,267,584 f32 = 77.1 MB

    k_w1_psum<<<dim3(128), dim3(256), 0, stream>>>(tok_w1, psum);
    k_w1_scan<<<dim3(1), dim3(256), 0, stream>>>(psum, offs);
    k_w1_prefix<<<dim3(128), dim3(256), 0, stream>>>(tok_w1, offs, w1ct);
    k_w2t_pack<<<dim3(128, 4), dim3(256), 0, stream>>>(tok_w2, w2t);
    k_pack1<<<dim3(256), dim3(256), 0, stream>>>(ch_w1, w1p);
    k_pack2<<<dim3(256), dim3(256), 0, stream>>>(ch_w2, w2p);
    k_lnT<<<dim3((B_ * N_) / 64), dim3(256), 0, stream>>>(x, ln1_g, ln1_b, y1t);
    k_tok1<<<dim3(16, 16), dim3(512), 0, stream>>>(y1t, w1ct, P);
    k_tok1_fin<<<dim3(512), dim3(256), 0, stream>>>(P, tok_b1, g1b);
    k_tok2mlp<<<dim3(64, 16), dim3(512), 0, stream>>>(g1b, w2t, tok_b2, ln2_g, ln2_b,
                                                      w1p, w2p, ch_b1, ch_b2, out);
}